// Round 2
// baseline (7955.368 us; speedup 1.0000x reference)
//
#include <hip/hip_runtime.h>

#define SEQ    59
#define FEAT   64
#define VOCAB  578
#define BATCH  4096
#define UNITS  1024
#define KLSTM  1088   // FEAT + UNITS; 17 K-tiles of 64, no padding
#define NPAD   640    // VOCAB padded to 5*128
#define NBLK   256    // grid blocks == CUs; 128KiB LDS forces 1 block/CU => all co-resident

typedef __bf16 bf16x8 __attribute__((ext_vector_type(8)));
typedef __bf16 bf16x4 __attribute__((ext_vector_type(4)));
typedef float  floatx4 __attribute__((ext_vector_type(4)));

typedef const __attribute__((address_space(1))) char gas_char;
typedef __attribute__((address_space(3))) char las_char;

__device__ __forceinline__ float sigmoid_f(float x) { return 1.f / (1.f + __expf(-x)); }
__device__ __forceinline__ float tanh_f(float x) { float e = __expf(2.f * x); return 1.f - 2.f / (e + 1.f); }

#define GLDS(srcp, dstp) __builtin_amdgcn_global_load_lds((gas_char*)(srcp), (las_char*)(dstp), 16, 0, 0)
#define BAR()   __builtin_amdgcn_s_barrier()
#define LGKM0() asm volatile("s_waitcnt lgkmcnt(0)" ::: "memory")
#define VMW(n)  asm volatile("s_waitcnt vmcnt(" #n ")" ::: "memory")
#define MFMA    __builtin_amdgcn_mfma_f32_16x16x32_bf16

// ---------------- conversion kernels ----------------

__global__ void convert_x_kernel(const float* __restrict__ x, __bf16* __restrict__ xbf) {
    int i = blockIdx.x * 256 + threadIdx.x;
    const int total = BATCH * SEQ * FEAT / 4;
    if (i >= total) return;
    float4 v = ((const float4*)x)[i];
    bf16x4 o;
    o.x = (__bf16)v.x; o.y = (__bf16)v.y; o.z = (__bf16)v.z; o.w = (__bf16)v.w;
    ((bf16x4*)xbf)[i] = o;
}

// Wtp [4096 rows][KLSTM k] bf16 row-major.
// row np = bc*256 + w*64 + g*16 + j  ->  gate g of unit u = bc*64 + w*16 + j
__global__ void convert_weights_kernel(const float* __restrict__ kern,
                                       const float* __restrict__ reck,
                                       __bf16* __restrict__ Wtp) {
    int idx = blockIdx.x * 256 + threadIdx.x;
    if (idx >= 4096 * KLSTM) return;
    int np = idx / KLSTM;
    int k  = idx - np * KLSTM;
    int bc = np >> 8;
    int w  = (np >> 6) & 3;
    int g  = (np >> 4) & 3;
    int j  = np & 15;
    int n  = g * 1024 + bc * 64 + w * 16 + j;
    float v = (k < FEAT) ? kern[(size_t)k * 4096 + n]
                         : reck[(size_t)(k - FEAT) * 4096 + n];
    Wtp[idx] = (__bf16)v;
}

__global__ void convert_w2_kernel(const float* __restrict__ w2, __bf16* __restrict__ Wt2p) {
    int idx = blockIdx.x * 256 + threadIdx.x;
    if (idx >= NPAD * 1024) return;
    int n = idx >> 10;
    int k = idx & 1023;
    float v = (n < VOCAB) ? w2[(size_t)k * VOCAB + n] : 0.f;
    Wt2p[idx] = (__bf16)v;
}

// ---------------- persistent LSTM: all 59 steps in one kernel ----------------
// 256x256 tile per block, 8 waves, 8-phase counted-vmcnt K-loop (shifted by one
// tile: tile0 = x computed in prologue, tiles 1..16 = h in the loop).
// c-state lives in registers across all steps. Grid barrier between steps:
// all 256 blocks are co-resident (LDS caps 1 block/CU, grid == #CUs), so a
// device-scope atomic counter barrier is deadlock-free.
__global__ void __launch_bounds__(512, 2) lstm_seq_kernel(
    const __bf16* __restrict__ xbf,
    const __bf16* __restrict__ Wtp,
    const float*  __restrict__ bias,
    __bf16*       __restrict__ hb0,
    __bf16*       __restrict__ hb1,
    unsigned*                  barcnt)
{
    __shared__ __bf16 Ash[2][2][256 * 32];  // [buf][kh]  64 KiB
    __shared__ __bf16 Bsh[2][2][128 * 64];  // [buf][nh]  64 KiB

    const int tid  = threadIdx.x;
    const int wid  = tid >> 6;
    const int lane = tid & 63;
    const int ln   = lane & 15;
    const int lk   = lane >> 4;
    const int wm   = wid >> 2;
    const int wn   = wid & 3;
    const int bc   = blockIdx.x;   // weight block on x => XCD = bc&7: weights stay L2-local
    const int rb   = blockIdx.y;

    // ---- staging slot maps ----
    const int af0 = tid, af1 = 512 + tid;
    const int ar0 = af0 >> 2, ar1 = af1 >> 2;
    const int ac0 = (af0 & 3) ^ ((ar0 >> 1) & 3);
    const int ac1 = (af1 & 3) ^ ((ar1 >> 1) & 3);
    const int br0 = af0 >> 3, br1 = af1 >> 3;
    const int bq0 = (af0 & 7) ^ (br0 & 7);
    const int bq1 = (af1 & 7) ^ (br1 & 7);

    const __bf16* wB0 = Wtp + (size_t)(bc * 256 + br0) * KLSTM + bq0 * 8;
    const __bf16* wB1 = Wtp + (size_t)(bc * 256 + br1) * KLSTM + bq1 * 8;
    const __bf16* xr0 = xbf + (size_t)(rb * 256 + ar0) * (SEQ * FEAT) + ac0 * 8;
    const __bf16* xr1 = xbf + (size_t)(rb * 256 + ar1) * (SEQ * FEAT) + ac1 * 8;
    const size_t  ho0 = (size_t)(rb * 256 + ar0) * UNITS + ac0 * 8;
    const size_t  ho1 = (size_t)(rb * 256 + ar1) * UNITS + ac1 * 8;

    const int adst0 = wid << 9;
    const int adst1 = 4096 + (wid << 9);

    // ---- read offsets ----
    int offA[8];
#pragma unroll
    for (int m = 0; m < 8; ++m) {
        int row = wm * 128 + m * 16 + ln;
        offA[m] = row * 32 + ((lk ^ ((row >> 1) & 3)) << 3);
    }
    int offB[4][2];
#pragma unroll
    for (int g = 0; g < 4; ++g) {
        int nr = (wn & 1) * 64 + g * 16 + ln;
#pragma unroll
        for (int kk = 0; kk < 2; ++kk)
            offB[g][kk] = nr * 64 + ((((kk << 2) + lk) ^ (nr & 7)) << 3);
    }
    const int nhsel = wn >> 1;
    const __bf16* B0  = Bsh[0][nhsel];
    const __bf16* B1  = Bsh[1][nhsel];
    const __bf16* A00 = Ash[0][0];
    const __bf16* A01 = Ash[0][1];
    const __bf16* A10 = Ash[1][0];
    const __bf16* A11 = Ash[1][1];

    const int u = bc * 64 + wn * 16 + ln;
    const float bi  = bias[u];
    const float bfv = bias[UNITS + u];
    const float bg  = bias[2 * UNITS + u];
    const float bo  = bias[3 * UNITS + u];

    float cc[8][4];
#pragma unroll
    for (int m = 0; m < 8; ++m)
#pragma unroll
        for (int r = 0; r < 4; ++r) cc[m][r] = 0.f;

    floatx4 acc[8][4];

#define STAH(BUF, KH, T) do { const int _c = ((T) - 1) * 64 + (KH) * 32; \
    GLDS(hA0 + _c, &Ash[BUF][KH][adst0]); \
    GLDS(hA1 + _c, &Ash[BUF][KH][adst1]); } while (0)
#define STBT(BUF, NH, T) do { const size_t _c = (size_t)(NH) * 128 * KLSTM + (T) * 64; \
    GLDS(wB0 + _c, &Bsh[BUF][NH][adst0]); \
    GLDS(wB1 + _c, &Bsh[BUF][NH][adst1]); } while (0)
#define PHASE_MFMA(MB, KKB) \
    __builtin_amdgcn_s_setprio(1); \
    _Pragma("unroll") \
    for (int m = 0; m < 4; ++m) \
    _Pragma("unroll") \
        for (int g = 0; g < 4; ++g) \
            acc[(MB) + m][g] = MFMA(aa[m], bb[KKB][g], acc[(MB) + m][g], 0, 0, 0); \
    __builtin_amdgcn_s_setprio(0)

#pragma unroll 1
    for (int t = 0; t < SEQ; ++t) {
        const __bf16* hin  = (t & 1) ? hb1 : hb0;
        __bf16*       hout = (t & 1) ? hb0 : hb1;
        const __bf16* hA0  = hin + ho0;
        const __bf16* hA1  = hin + ho1;
        const __bf16* xA0  = xr0 + t * FEAT;
        const __bf16* xA1  = xr1 + t * FEAT;

#pragma unroll
        for (int m = 0; m < 8; ++m)
#pragma unroll
            for (int g = 0; g < 4; ++g)
                acc[m][g] = (floatx4){0.f, 0.f, 0.f, 0.f};

        // ---- pre-barrier staging (h-independent): tile0 (x A + B), tile1 B ----
        STBT(0, 1, 0);
        GLDS(xA0, &Ash[0][0][adst0]); GLDS(xA1, &Ash[0][0][adst1]);
        STBT(0, 0, 0);
        GLDS(xA0 + 32, &Ash[0][1][adst0]); GLDS(xA1 + 32, &Ash[0][1][adst1]);
        STBT(1, 1, 1);
        STBT(1, 0, 1);

        // ---- grid barrier: h(t-1) complete + visible device-wide ----
        __threadfence();            // drain + write back own h stores (L2 -> coherence point)
        __syncthreads();
        if (tid == 0) {
            __hip_atomic_fetch_add(barcnt, 1u, __ATOMIC_ACQ_REL, __HIP_MEMORY_SCOPE_AGENT);
            const unsigned tgt = (unsigned)(t + 1) * NBLK;
            while (__hip_atomic_load(barcnt, __ATOMIC_RELAXED, __HIP_MEMORY_SCOPE_AGENT) < tgt)
                __builtin_amdgcn_s_sleep(2);
            (void)__hip_atomic_load(barcnt, __ATOMIC_ACQUIRE, __HIP_MEMORY_SCOPE_AGENT); // inv
        }
        __syncthreads();

        // ---- post-barrier: tile1 A (h cols 0..63) ----
        STAH(1, 0, 1);
        STAH(1, 1, 1);
        VMW(8);                      // tile0 (oldest 8 loads) landed
        BAR();
        // ---- tile0 compute (x @ W_x), from buf0 ----
        {
            bf16x8 bb[2][4], aa[4];
#pragma unroll
            for (int g = 0; g < 4; ++g) {
                bb[0][g] = *(const bf16x8*)(B0 + offB[g][0]);
                bb[1][g] = *(const bf16x8*)(B0 + offB[g][1]);
            }
#pragma unroll
            for (int m = 0; m < 4; ++m) aa[m] = *(const bf16x8*)(A00 + offA[m]);
            LGKM0(); PHASE_MFMA(0, 0);
#pragma unroll
            for (int m = 0; m < 4; ++m) aa[m] = *(const bf16x8*)(A00 + offA[4 + m]);
            LGKM0(); PHASE_MFMA(4, 0);
#pragma unroll
            for (int m = 0; m < 4; ++m) aa[m] = *(const bf16x8*)(A01 + offA[m]);
            LGKM0(); PHASE_MFMA(0, 1);
#pragma unroll
            for (int m = 0; m < 4; ++m) aa[m] = *(const bf16x8*)(A01 + offA[4 + m]);
            LGKM0(); PHASE_MFMA(4, 1);
        }
        BAR();
        // stage tile2 into buf0 (order mimics steady P5,P6,P7)
        STBT(0, 1, 2);
        STAH(0, 0, 2);
        STBT(0, 0, 2);
        VMW(6);                      // tile1 B+A fully landed; 6 tile2 loads in flight
        BAR();

        // ---- main loop: tiles 1..16, T1=2it+1 (buf1, P0-P3), T2=2it+2 (buf0, P4-P7) ----
#pragma unroll 1
        for (int it = 0; it < 8; ++it) {
            const int T2 = 2 * it + 2;
            const int T3 = (2 * it + 3 < 17) ? (2 * it + 3) : 16;  // clamped re-stage keeps
            const int T4 = (2 * it + 4 < 17) ? (2 * it + 4) : 16;  // vmcnt accounting exact
            bf16x8 bb[2][4], aa[4];
            // P0
#pragma unroll
            for (int g = 0; g < 4; ++g) {
                bb[0][g] = *(const bf16x8*)(B1 + offB[g][0]);
                bb[1][g] = *(const bf16x8*)(B1 + offB[g][1]);
            }
#pragma unroll
            for (int m = 0; m < 4; ++m) aa[m] = *(const bf16x8*)(A10 + offA[m]);
            STAH(0, 1, T2);
            BAR(); LGKM0(); PHASE_MFMA(0, 0); BAR();
            // P1
#pragma unroll
            for (int m = 0; m < 4; ++m) aa[m] = *(const bf16x8*)(A10 + offA[4 + m]);
            STBT(1, 1, T3);
            BAR(); LGKM0(); PHASE_MFMA(4, 0); BAR();
            // P2
#pragma unroll
            for (int m = 0; m < 4; ++m) aa[m] = *(const bf16x8*)(A11 + offA[m]);
            STAH(1, 0, T3);
            BAR(); LGKM0(); PHASE_MFMA(0, 1); BAR();
            // P3
#pragma unroll
            for (int m = 0; m < 4; ++m) aa[m] = *(const bf16x8*)(A11 + offA[4 + m]);
            STBT(1, 0, T3);
            BAR(); LGKM0(); PHASE_MFMA(4, 1); VMW(6); BAR();
            // P4
#pragma unroll
            for (int g = 0; g < 4; ++g) {
                bb[0][g] = *(const bf16x8*)(B0 + offB[g][0]);
                bb[1][g] = *(const bf16x8*)(B0 + offB[g][1]);
            }
#pragma unroll
            for (int m = 0; m < 4; ++m) aa[m] = *(const bf16x8*)(A00 + offA[m]);
            STAH(1, 1, T3);
            BAR(); LGKM0(); PHASE_MFMA(0, 0); BAR();
            // P5
#pragma unroll
            for (int m = 0; m < 4; ++m) aa[m] = *(const bf16x8*)(A00 + offA[4 + m]);
            STBT(0, 1, T4);
            BAR(); LGKM0(); PHASE_MFMA(4, 0); BAR();
            // P6
#pragma unroll
            for (int m = 0; m < 4; ++m) aa[m] = *(const bf16x8*)(A01 + offA[m]);
            STAH(0, 0, T4);
            BAR(); LGKM0(); PHASE_MFMA(0, 1); BAR();
            // P7
#pragma unroll
            for (int m = 0; m < 4; ++m) aa[m] = *(const bf16x8*)(A01 + offA[4 + m]);
            STBT(0, 0, T4);
            BAR(); LGKM0(); PHASE_MFMA(4, 1); VMW(6); BAR();
        }
        VMW(0);   // drain clamped tail stages before LDS regions are re-staged next step

        // ---- fused LSTM epilogue: c stays in registers, h -> global ----
#pragma unroll
        for (int m = 0; m < 8; ++m) {
            const int row0 = rb * 256 + wm * 128 + m * 16 + lk * 4;
#pragma unroll
            for (int r = 0; r < 4; ++r) {
                float ig = sigmoid_f(acc[m][0][r] + bi);
                float fg = sigmoid_f(acc[m][1][r] + bfv);
                float gg = tanh_f(acc[m][2][r] + bg);
                float og = sigmoid_f(acc[m][3][r] + bo);
                float cn = fg * cc[m][r] + ig * gg;
                cc[m][r] = cn;
                hout[(size_t)(row0 + r) * UNITS + u] = (__bf16)(og * tanh_f(cn));
            }
        }
    }
#undef STAH
#undef STBT
}

// ---------------- final dense: [4096,1024] @ [1024,640] -> logits fp32 ----------------
__global__ void __launch_bounds__(256) dense_kernel(
    const __bf16* __restrict__ hin,
    const __bf16* __restrict__ Wt2p,
    float*        __restrict__ logits)
{
    __shared__ __bf16 As[128 * 64];
    __shared__ __bf16 Bs[128 * 64];

    const int tid  = threadIdx.x;
    const int wid  = tid >> 6;
    const int lane = tid & 63;
    const int ln   = lane & 15;
    const int lk   = lane >> 4;
    const int wm   = wid >> 1;
    const int wn   = wid & 1;
    const int rb   = blockIdx.x;
    const int nb   = blockIdx.y;

    floatx4 acc[4][4];
#pragma unroll
    for (int m = 0; m < 4; ++m)
#pragma unroll
        for (int g = 0; g < 4; ++g)
            acc[m][g] = (floatx4){0.f, 0.f, 0.f, 0.f};

    int s_row[4], s_kgd[4];
#pragma unroll
    for (int q = 0; q < 4; ++q) {
        int flat = q * 256 + tid;
        int row  = flat >> 3;
        s_row[q] = row;
        s_kgd[q] = (flat & 7) ^ (row & 7);
    }

    for (int kt = 0; kt < 16; ++kt) {
        __syncthreads();
#pragma unroll
        for (int q = 0; q < 4; ++q) {
            const int row = s_row[q], kgd = s_kgd[q];
            const __bf16* gp = hin + ((size_t)(rb * 128 + row) << 10) + kt * 64 + kgd * 8;
            GLDS(gp, As + (size_t)(q * 256 + (wid << 6)) * 8);
        }
#pragma unroll
        for (int q = 0; q < 4; ++q) {
            const int n = s_row[q], kgd = s_kgd[q];
            const __bf16* gp = Wt2p + ((size_t)(nb * 128 + n) << 10) + kt * 64 + kgd * 8;
            GLDS(gp, Bs + (size_t)(q * 256 + (wid << 6)) * 8);
        }
        __syncthreads();
#pragma unroll
        for (int kk = 0; kk < 2; ++kk) {
            const int kg = kk * 4 + lk;
            bf16x8 a[4], b[4];
#pragma unroll
            for (int m = 0; m < 4; ++m) {
                int row  = wm * 64 + m * 16 + ln;
                int ccol = (kg ^ (row & 7)) * 8;
                a[m] = *(const bf16x8*)(As + row * 64 + ccol);
            }
#pragma unroll
            for (int g = 0; g < 4; ++g) {
                int n    = g * 32 + wn * 16 + ln;
                int ccol = (kg ^ (n & 7)) * 8;
                b[g] = *(const bf16x8*)(Bs + n * 64 + ccol);
            }
#pragma unroll
            for (int m = 0; m < 4; ++m)
#pragma unroll
                for (int g = 0; g < 4; ++g)
                    acc[m][g] = MFMA(a[m], b[g], acc[m][g], 0, 0, 0);
        }
    }

#pragma unroll
    for (int m = 0; m < 4; ++m) {
        const int row0 = rb * 128 + wm * 64 + m * 16 + lk * 4;
#pragma unroll
        for (int g = 0; g < 4; ++g) {
            const int n = nb * 128 + g * 32 + wn * 16 + ln;
#pragma unroll
            for (int r = 0; r < 4; ++r)
                logits[(size_t)(row0 + r) * NPAD + n] = acc[m][g][r];
        }
    }
}

// ---------------- row softmax over 578 cols (+b2) ----------------
__global__ void __launch_bounds__(256) softmax_kernel(
    const float* __restrict__ logits,
    const float* __restrict__ b2,
    float* __restrict__ out)
{
    const int row = blockIdx.x;
    const int tid = threadIdx.x;
    __shared__ float red[8];

    float z[3];
    float lmax = -1e30f;
#pragma unroll
    for (int j = 0; j < 3; ++j) {
        int col = tid + j * 256;
        if (col < VOCAB) {
            z[j] = logits[(size_t)row * NPAD + col] + b2[col];
            lmax = fmaxf(lmax, z[j]);
        } else z[j] = -1e30f;
    }
    for (int off = 32; off > 0; off >>= 1) lmax = fmaxf(lmax, __shfl_xor(lmax, off));
    if ((tid & 63) == 0) red[tid >> 6] = lmax;
    __syncthreads();
    lmax = fmaxf(fmaxf(red[0], red[1]), fmaxf(red[2], red[3]));
    __syncthreads();

    float lsum = 0.f;
#pragma unroll
    for (int j = 0; j < 3; ++j) {
        int col = tid + j * 256;
        if (col < VOCAB) { z[j] = __expf(z[j] - lmax); lsum += z[j]; }
    }
    for (int off = 32; off > 0; off >>= 1) lsum += __shfl_xor(lsum, off);
    if ((tid & 63) == 0) red[tid >> 6] = lsum;
    __syncthreads();
    lsum = red[0] + red[1] + red[2] + red[3];
    float inv = 1.f / lsum;
#pragma unroll
    for (int j = 0; j < 3; ++j) {
        int col = tid + j * 256;
        if (col < VOCAB) out[(size_t)row * VOCAB + col] = z[j] * inv;
    }
}

// ---------------- launch ----------------
extern "C" void kernel_launch(void* const* d_in, const int* in_sizes, int n_in,
                              void* d_out, int out_size, void* d_ws, size_t ws_size,
                              hipStream_t stream)
{
    const float* x    = (const float*)d_in[0];
    const float* kern = (const float*)d_in[1];
    const float* reck = (const float*)d_in[2];
    const float* bias = (const float*)d_in[3];
    const float* w2   = (const float*)d_in[4];
    const float* b2   = (const float*)d_in[5];
    float* out = (float*)d_out;

    char* ws = (char*)d_ws;
    size_t off = 0;
    auto alloc = [&](size_t bytes) {
        char* p = ws + off;
        off += (bytes + 255) & ~(size_t)255;
        return p;
    };
    __bf16*   Wtp    = (__bf16*)alloc((size_t)4096 * KLSTM * 2);
    __bf16*   Wt2p   = (__bf16*)alloc((size_t)NPAD * 1024 * 2);
    __bf16*   xbf    = (__bf16*)alloc((size_t)BATCH * SEQ * FEAT * 2);
    __bf16*   h0     = (__bf16*)alloc((size_t)BATCH * UNITS * 2);
    __bf16*   h1     = (__bf16*)alloc((size_t)BATCH * UNITS * 2);
    float*    logits = (float*)alloc((size_t)BATCH * NPAD * 4);
    unsigned* barcnt = (unsigned*)alloc(256);
    if (off > ws_size) return;  // loud failure: output stays zero

    (void)hipMemsetAsync(h0, 0, (size_t)BATCH * UNITS * 2, stream);
    (void)hipMemsetAsync(barcnt, 0, 256, stream);

    convert_x_kernel<<<(BATCH * SEQ * FEAT / 4 + 255) / 256, 256, 0, stream>>>(x, xbf);
    convert_weights_kernel<<<(4096 * KLSTM + 255) / 256, 256, 0, stream>>>(kern, reck, Wtp);
    convert_w2_kernel<<<(NPAD * 1024 + 255) / 256, 256, 0, stream>>>(w2, Wt2p);

    // one persistent dispatch for all SEQ steps; final h lands in h1 (SEQ odd)
    lstm_seq_kernel<<<dim3(16, 16), 512, 0, stream>>>(xbf, Wtp, bias, h0, h1, barcnt);

    dense_kernel<<<dim3(32, 5), 256, 0, stream>>>(h1, Wt2p, logits);
    softmax_kernel<<<BATCH, 256, 0, stream>>>(logits, b2, out);
}

// Round 3
// 4385.358 us; speedup vs baseline: 1.8141x; 1.8141x over previous
//
#include <hip/hip_runtime.h>

#define SEQ    59
#define FEAT   64
#define VOCAB  578
#define BATCH  4096
#define UNITS  1024
#define KLSTM  1088   // FEAT + UNITS; 17 K-tiles of 64, no padding
#define NPAD   640    // VOCAB padded to 5*128
#define NBLK   256    // grid blocks == CUs; 128KiB LDS forces 1 block/CU => all co-resident

typedef __bf16 bf16x8 __attribute__((ext_vector_type(8)));
typedef __bf16 bf16x4 __attribute__((ext_vector_type(4)));
typedef float  floatx4 __attribute__((ext_vector_type(4)));

typedef const __attribute__((address_space(1))) char gas_char;
typedef __attribute__((address_space(3))) char las_char;

__device__ __forceinline__ float sigmoid_f(float x) { return 1.f / (1.f + __expf(-x)); }
__device__ __forceinline__ float tanh_f(float x) { float e = __expf(2.f * x); return 1.f - 2.f / (e + 1.f); }

// normal (cacheable) staging: weights + x, read-only data
#define GLDS(srcp, dstp)  __builtin_amdgcn_global_load_lds((gas_char*)(srcp), (las_char*)(dstp), 16, 0, 0)
// device-coherent staging: h tiles. aux=0x11 = CPol SC0|SC1 (gfx940+): bypass XCD-local L2,
// read from the L3 coherence point where producers' sc0sc1 write-through stores land.
#define GLDSC(srcp, dstp) __builtin_amdgcn_global_load_lds((gas_char*)(srcp), (las_char*)(dstp), 16, 0, 0x11)
#define BAR()   __builtin_amdgcn_s_barrier()
#define LGKM0() asm volatile("s_waitcnt lgkmcnt(0)" ::: "memory")
#define VMW(n)  asm volatile("s_waitcnt vmcnt(" #n ")" ::: "memory")
#define MFMA    __builtin_amdgcn_mfma_f32_16x16x32_bf16

// ---------------- conversion kernels ----------------

__global__ void convert_x_kernel(const float* __restrict__ x, __bf16* __restrict__ xbf) {
    int i = blockIdx.x * 256 + threadIdx.x;
    const int total = BATCH * SEQ * FEAT / 4;
    if (i >= total) return;
    float4 v = ((const float4*)x)[i];
    bf16x4 o;
    o.x = (__bf16)v.x; o.y = (__bf16)v.y; o.z = (__bf16)v.z; o.w = (__bf16)v.w;
    ((bf16x4*)xbf)[i] = o;
}

// Wtp [4096 rows][KLSTM k] bf16 row-major.
// row np = bc*256 + w*64 + g*16 + j  ->  gate g of unit u = bc*64 + w*16 + j
__global__ void convert_weights_kernel(const float* __restrict__ kern,
                                       const float* __restrict__ reck,
                                       __bf16* __restrict__ Wtp) {
    int idx = blockIdx.x * 256 + threadIdx.x;
    if (idx >= 4096 * KLSTM) return;
    int np = idx / KLSTM;
    int k  = idx - np * KLSTM;
    int bc = np >> 8;
    int w  = (np >> 6) & 3;
    int g  = (np >> 4) & 3;
    int j  = np & 15;
    int n  = g * 1024 + bc * 64 + w * 16 + j;
    float v = (k < FEAT) ? kern[(size_t)k * 4096 + n]
                         : reck[(size_t)(k - FEAT) * 4096 + n];
    Wtp[idx] = (__bf16)v;
}

__global__ void convert_w2_kernel(const float* __restrict__ w2, __bf16* __restrict__ Wt2p) {
    int idx = blockIdx.x * 256 + threadIdx.x;
    if (idx >= NPAD * 1024) return;
    int n = idx >> 10;
    int k = idx & 1023;
    float v = (n < VOCAB) ? w2[(size_t)k * VOCAB + n] : 0.f;
    Wt2p[idx] = (__bf16)v;
}

// ---------------- persistent LSTM: all 59 steps in one kernel ----------------
// Identical schedule to the (correct) round-2 kernel. Coherence redesigned:
//  - h stores: global_store_short sc0 sc1 (write-through to L3, no dirty L2 lines)
//  - h loads:  global_load_lds aux=0x11   (bypass local L2 -> L3)
//  - barrier:  RELAXED atomics + s_waitcnt vmcnt(0) release; NO threadfence/acquire,
//              so no buffer_wbl2/buffer_inv -> weights stay L2-resident all 59 steps.
__global__ void __launch_bounds__(512, 2) lstm_seq_kernel(
    const __bf16* __restrict__ xbf,
    const __bf16* __restrict__ Wtp,
    const float*  __restrict__ bias,
    __bf16*       __restrict__ hb0,
    __bf16*       __restrict__ hb1,
    unsigned*                  barcnt)
{
    __shared__ __bf16 Ash[2][2][256 * 32];  // [buf][kh]  64 KiB
    __shared__ __bf16 Bsh[2][2][128 * 64];  // [buf][nh]  64 KiB

    const int tid  = threadIdx.x;
    const int wid  = tid >> 6;
    const int lane = tid & 63;
    const int ln   = lane & 15;
    const int lk   = lane >> 4;
    const int wm   = wid >> 2;
    const int wn   = wid & 3;
    const int bc   = blockIdx.x;   // weight block on x => XCD = bc&7: weights stay L2-local
    const int rb   = blockIdx.y;

    // ---- staging slot maps ----
    const int af0 = tid, af1 = 512 + tid;
    const int ar0 = af0 >> 2, ar1 = af1 >> 2;
    const int ac0 = (af0 & 3) ^ ((ar0 >> 1) & 3);
    const int ac1 = (af1 & 3) ^ ((ar1 >> 1) & 3);
    const int br0 = af0 >> 3, br1 = af1 >> 3;
    const int bq0 = (af0 & 7) ^ (br0 & 7);
    const int bq1 = (af1 & 7) ^ (br1 & 7);

    const __bf16* wB0 = Wtp + (size_t)(bc * 256 + br0) * KLSTM + bq0 * 8;
    const __bf16* wB1 = Wtp + (size_t)(bc * 256 + br1) * KLSTM + bq1 * 8;
    const __bf16* xr0 = xbf + (size_t)(rb * 256 + ar0) * (SEQ * FEAT) + ac0 * 8;
    const __bf16* xr1 = xbf + (size_t)(rb * 256 + ar1) * (SEQ * FEAT) + ac1 * 8;
    const size_t  ho0 = (size_t)(rb * 256 + ar0) * UNITS + ac0 * 8;
    const size_t  ho1 = (size_t)(rb * 256 + ar1) * UNITS + ac1 * 8;

    const int adst0 = wid << 9;
    const int adst1 = 4096 + (wid << 9);

    // ---- read offsets ----
    int offA[8];
#pragma unroll
    for (int m = 0; m < 8; ++m) {
        int row = wm * 128 + m * 16 + ln;
        offA[m] = row * 32 + ((lk ^ ((row >> 1) & 3)) << 3);
    }
    int offB[4][2];
#pragma unroll
    for (int g = 0; g < 4; ++g) {
        int nr = (wn & 1) * 64 + g * 16 + ln;
#pragma unroll
        for (int kk = 0; kk < 2; ++kk)
            offB[g][kk] = nr * 64 + ((((kk << 2) + lk) ^ (nr & 7)) << 3);
    }
    const int nhsel = wn >> 1;
    const __bf16* B0  = Bsh[0][nhsel];
    const __bf16* B1  = Bsh[1][nhsel];
    const __bf16* A00 = Ash[0][0];
    const __bf16* A01 = Ash[0][1];
    const __bf16* A10 = Ash[1][0];
    const __bf16* A11 = Ash[1][1];

    const int u = bc * 64 + wn * 16 + ln;
    const float bi  = bias[u];
    const float bfv = bias[UNITS + u];
    const float bg  = bias[2 * UNITS + u];
    const float bo  = bias[3 * UNITS + u];

    float cc[8][4];
#pragma unroll
    for (int m = 0; m < 8; ++m)
#pragma unroll
        for (int r = 0; r < 4; ++r) cc[m][r] = 0.f;

    floatx4 acc[8][4];

#define STAH(BUF, KH, T) do { const int _c = ((T) - 1) * 64 + (KH) * 32; \
    GLDSC(hA0 + _c, &Ash[BUF][KH][adst0]); \
    GLDSC(hA1 + _c, &Ash[BUF][KH][adst1]); } while (0)
#define STBT(BUF, NH, T) do { const size_t _c = (size_t)(NH) * 128 * KLSTM + (T) * 64; \
    GLDS(wB0 + _c, &Bsh[BUF][NH][adst0]); \
    GLDS(wB1 + _c, &Bsh[BUF][NH][adst1]); } while (0)
#define PHASE_MFMA(MB, KKB) \
    __builtin_amdgcn_s_setprio(1); \
    _Pragma("unroll") \
    for (int m = 0; m < 4; ++m) \
    _Pragma("unroll") \
        for (int g = 0; g < 4; ++g) \
            acc[(MB) + m][g] = MFMA(aa[m], bb[KKB][g], acc[(MB) + m][g], 0, 0, 0); \
    __builtin_amdgcn_s_setprio(0)

#pragma unroll 1
    for (int t = 0; t < SEQ; ++t) {
        const __bf16* hin  = (t & 1) ? hb1 : hb0;
        __bf16*       hout = (t & 1) ? hb0 : hb1;
        const __bf16* hA0  = hin + ho0;
        const __bf16* hA1  = hin + ho1;
        const __bf16* xA0  = xr0 + t * FEAT;
        const __bf16* xA1  = xr1 + t * FEAT;

#pragma unroll
        for (int m = 0; m < 8; ++m)
#pragma unroll
            for (int g = 0; g < 4; ++g)
                acc[m][g] = (floatx4){0.f, 0.f, 0.f, 0.f};

        // ---- pre-barrier staging (h-independent): tile0 (x A + B), tile1 B ----
        STBT(0, 1, 0);
        GLDS(xA0, &Ash[0][0][adst0]); GLDS(xA1, &Ash[0][0][adst1]);
        STBT(0, 0, 0);
        GLDS(xA0 + 32, &Ash[0][1][adst0]); GLDS(xA1 + 32, &Ash[0][1][adst1]);
        STBT(1, 1, 1);
        STBT(1, 0, 1);

        // ---- grid barrier (RELAXED; release = vmcnt(0) on sc1 write-through stores) ----
        VMW(0);                     // prior h stores visible at L3; prefetch landed in LDS
        __syncthreads();
        if (tid == 0) {
            __hip_atomic_fetch_add(barcnt, 1u, __ATOMIC_RELAXED, __HIP_MEMORY_SCOPE_AGENT);
            const unsigned tgt = (unsigned)(t + 1) * NBLK;
            while (__hip_atomic_load(barcnt, __ATOMIC_RELAXED, __HIP_MEMORY_SCOPE_AGENT) < tgt)
                __builtin_amdgcn_s_sleep(2);
        }
        __syncthreads();

        // ---- post-barrier: tile1 A (h cols 0..63), L2-bypassing coherent loads ----
        STAH(1, 0, 1);
        STAH(1, 1, 1);
        VMW(8);                      // tile0 already resident (drained above)
        BAR();
        // ---- tile0 compute (x @ W_x), from buf0 ----
        {
            bf16x8 bb[2][4], aa[4];
#pragma unroll
            for (int g = 0; g < 4; ++g) {
                bb[0][g] = *(const bf16x8*)(B0 + offB[g][0]);
                bb[1][g] = *(const bf16x8*)(B0 + offB[g][1]);
            }
#pragma unroll
            for (int m = 0; m < 4; ++m) aa[m] = *(const bf16x8*)(A00 + offA[m]);
            LGKM0(); PHASE_MFMA(0, 0);
#pragma unroll
            for (int m = 0; m < 4; ++m) aa[m] = *(const bf16x8*)(A00 + offA[4 + m]);
            LGKM0(); PHASE_MFMA(4, 0);
#pragma unroll
            for (int m = 0; m < 4; ++m) aa[m] = *(const bf16x8*)(A01 + offA[m]);
            LGKM0(); PHASE_MFMA(0, 1);
#pragma unroll
            for (int m = 0; m < 4; ++m) aa[m] = *(const bf16x8*)(A01 + offA[4 + m]);
            LGKM0(); PHASE_MFMA(4, 1);
        }
        BAR();
        // stage tile2 into buf0 (order mimics steady P5,P6,P7)
        STBT(0, 1, 2);
        STAH(0, 0, 2);
        STBT(0, 0, 2);
        VMW(6);                      // tile1 B+A fully landed; 6 tile2 loads in flight
        BAR();

        // ---- main loop: tiles 1..16, T1=2it+1 (buf1, P0-P3), T2=2it+2 (buf0, P4-P7) ----
#pragma unroll 1
        for (int it = 0; it < 8; ++it) {
            const int T2 = 2 * it + 2;
            const int T3 = (2 * it + 3 < 17) ? (2 * it + 3) : 16;  // clamped re-stage keeps
            const int T4 = (2 * it + 4 < 17) ? (2 * it + 4) : 16;  // vmcnt accounting exact
            bf16x8 bb[2][4], aa[4];
            // P0
#pragma unroll
            for (int g = 0; g < 4; ++g) {
                bb[0][g] = *(const bf16x8*)(B1 + offB[g][0]);
                bb[1][g] = *(const bf16x8*)(B1 + offB[g][1]);
            }
#pragma unroll
            for (int m = 0; m < 4; ++m) aa[m] = *(const bf16x8*)(A10 + offA[m]);
            STAH(0, 1, T2);
            BAR(); LGKM0(); PHASE_MFMA(0, 0); BAR();
            // P1
#pragma unroll
            for (int m = 0; m < 4; ++m) aa[m] = *(const bf16x8*)(A10 + offA[4 + m]);
            STBT(1, 1, T3);
            BAR(); LGKM0(); PHASE_MFMA(4, 0); BAR();
            // P2
#pragma unroll
            for (int m = 0; m < 4; ++m) aa[m] = *(const bf16x8*)(A11 + offA[m]);
            STAH(1, 0, T3);
            BAR(); LGKM0(); PHASE_MFMA(0, 1); BAR();
            // P3
#pragma unroll
            for (int m = 0; m < 4; ++m) aa[m] = *(const bf16x8*)(A11 + offA[4 + m]);
            STBT(1, 0, T3);
            BAR(); LGKM0(); PHASE_MFMA(4, 1); VMW(6); BAR();
            // P4
#pragma unroll
            for (int g = 0; g < 4; ++g) {
                bb[0][g] = *(const bf16x8*)(B0 + offB[g][0]);
                bb[1][g] = *(const bf16x8*)(B0 + offB[g][1]);
            }
#pragma unroll
            for (int m = 0; m < 4; ++m) aa[m] = *(const bf16x8*)(A00 + offA[m]);
            STAH(1, 1, T3);
            BAR(); LGKM0(); PHASE_MFMA(0, 0); BAR();
            // P5
#pragma unroll
            for (int m = 0; m < 4; ++m) aa[m] = *(const bf16x8*)(A00 + offA[4 + m]);
            STBT(0, 1, T4);
            BAR(); LGKM0(); PHASE_MFMA(4, 0); BAR();
            // P6
#pragma unroll
            for (int m = 0; m < 4; ++m) aa[m] = *(const bf16x8*)(A01 + offA[m]);
            STAH(0, 0, T4);
            BAR(); LGKM0(); PHASE_MFMA(0, 1); BAR();
            // P7
#pragma unroll
            for (int m = 0; m < 4; ++m) aa[m] = *(const bf16x8*)(A01 + offA[4 + m]);
            STBT(0, 0, T4);
            BAR(); LGKM0(); PHASE_MFMA(4, 1); VMW(6); BAR();
        }
        VMW(0);   // drain clamped tail stages before LDS regions are re-staged next step

        // ---- fused LSTM epilogue: c stays in registers; h -> global write-through (sc0 sc1) ----
#pragma unroll
        for (int m = 0; m < 8; ++m) {
            const int row0 = rb * 256 + wm * 128 + m * 16 + lk * 4;
#pragma unroll
            for (int r = 0; r < 4; ++r) {
                float ig = sigmoid_f(acc[m][0][r] + bi);
                float fg = sigmoid_f(acc[m][1][r] + bfv);
                float gg = tanh_f(acc[m][2][r] + bg);
                float og = sigmoid_f(acc[m][3][r] + bo);
                float cn = fg * cc[m][r] + ig * gg;
                cc[m][r] = cn;
                __bf16 hv = (__bf16)(og * tanh_f(cn));
                unsigned hbits = (unsigned)__builtin_bit_cast(unsigned short, hv);
                const __bf16* hp = hout + (size_t)(row0 + r) * UNITS + u;
                asm volatile("global_store_short %0, %1, off sc0 sc1"
                             :: "v"(hp), "v"(hbits) : "memory");
            }
        }
    }
#undef STAH
#undef STBT
}

// ---------------- final dense: [4096,1024] @ [1024,640] -> logits fp32 ----------------
__global__ void __launch_bounds__(256) dense_kernel(
    const __bf16* __restrict__ hin,
    const __bf16* __restrict__ Wt2p,
    float*        __restrict__ logits)
{
    __shared__ __bf16 As[128 * 64];
    __shared__ __bf16 Bs[128 * 64];

    const int tid  = threadIdx.x;
    const int wid  = tid >> 6;
    const int lane = tid & 63;
    const int ln   = lane & 15;
    const int lk   = lane >> 4;
    const int wm   = wid >> 1;
    const int wn   = wid & 1;
    const int rb   = blockIdx.x;
    const int nb   = blockIdx.y;

    floatx4 acc[4][4];
#pragma unroll
    for (int m = 0; m < 4; ++m)
#pragma unroll
        for (int g = 0; g < 4; ++g)
            acc[m][g] = (floatx4){0.f, 0.f, 0.f, 0.f};

    int s_row[4], s_kgd[4];
#pragma unroll
    for (int q = 0; q < 4; ++q) {
        int flat = q * 256 + tid;
        int row  = flat >> 3;
        s_row[q] = row;
        s_kgd[q] = (flat & 7) ^ (row & 7);
    }

    for (int kt = 0; kt < 16; ++kt) {
        __syncthreads();
#pragma unroll
        for (int q = 0; q < 4; ++q) {
            const int row = s_row[q], kgd = s_kgd[q];
            const __bf16* gp = hin + ((size_t)(rb * 128 + row) << 10) + kt * 64 + kgd * 8;
            GLDS(gp, As + (size_t)(q * 256 + (wid << 6)) * 8);
        }
#pragma unroll
        for (int q = 0; q < 4; ++q) {
            const int n = s_row[q], kgd = s_kgd[q];
            const __bf16* gp = Wt2p + ((size_t)(nb * 128 + n) << 10) + kt * 64 + kgd * 8;
            GLDS(gp, Bs + (size_t)(q * 256 + (wid << 6)) * 8);
        }
        __syncthreads();
#pragma unroll
        for (int kk = 0; kk < 2; ++kk) {
            const int kg = kk * 4 + lk;
            bf16x8 a[4], b[4];
#pragma unroll
            for (int m = 0; m < 4; ++m) {
                int row  = wm * 64 + m * 16 + ln;
                int ccol = (kg ^ (row & 7)) * 8;
                a[m] = *(const bf16x8*)(As + row * 64 + ccol);
            }
#pragma unroll
            for (int g = 0; g < 4; ++g) {
                int n    = g * 32 + wn * 16 + ln;
                int ccol = (kg ^ (n & 7)) * 8;
                b[g] = *(const bf16x8*)(Bs + n * 64 + ccol);
            }
#pragma unroll
            for (int m = 0; m < 4; ++m)
#pragma unroll
                for (int g = 0; g < 4; ++g)
                    acc[m][g] = MFMA(a[m], b[g], acc[m][g], 0, 0, 0);
        }
    }

#pragma unroll
    for (int m = 0; m < 4; ++m) {
        const int row0 = rb * 128 + wm * 64 + m * 16 + lk * 4;
#pragma unroll
        for (int g = 0; g < 4; ++g) {
            const int n = nb * 128 + g * 32 + wn * 16 + ln;
#pragma unroll
            for (int r = 0; r < 4; ++r)
                logits[(size_t)(row0 + r) * NPAD + n] = acc[m][g][r];
        }
    }
}

// ---------------- row softmax over 578 cols (+b2) ----------------
__global__ void __launch_bounds__(256) softmax_kernel(
    const float* __restrict__ logits,
    const float* __restrict__ b2,
    float* __restrict__ out)
{
    const int row = blockIdx.x;
    const int tid = threadIdx.x;
    __shared__ float red[8];

    float z[3];
    float lmax = -1e30f;
#pragma unroll
    for (int j = 0; j < 3; ++j) {
        int col = tid + j * 256;
        if (col < VOCAB) {
            z[j] = logits[(size_t)row * NPAD + col] + b2[col];
            lmax = fmaxf(lmax, z[j]);
        } else z[j] = -1e30f;
    }
    for (int off = 32; off > 0; off >>= 1) lmax = fmaxf(lmax, __shfl_xor(lmax, off));
    if ((tid & 63) == 0) red[tid >> 6] = lmax;
    __syncthreads();
    lmax = fmaxf(fmaxf(red[0], red[1]), fmaxf(red[2], red[3]));
    __syncthreads();

    float lsum = 0.f;
#pragma unroll
    for (int j = 0; j < 3; ++j) {
        int col = tid + j * 256;
        if (col < VOCAB) { z[j] = __expf(z[j] - lmax); lsum += z[j]; }
    }
    for (int off = 32; off > 0; off >>= 1) lsum += __shfl_xor(lsum, off);
    if ((tid & 63) == 0) red[tid >> 6] = lsum;
    __syncthreads();
    lsum = red[0] + red[1] + red[2] + red[3];
    float inv = 1.f / lsum;
#pragma unroll
    for (int j = 0; j < 3; ++j) {
        int col = tid + j * 256;
        if (col < VOCAB) out[(size_t)row * VOCAB + col] = z[j] * inv;
    }
}

// ---------------- launch ----------------
extern "C" void kernel_launch(void* const* d_in, const int* in_sizes, int n_in,
                              void* d_out, int out_size, void* d_ws, size_t ws_size,
                              hipStream_t stream)
{
    const float* x    = (const float*)d_in[0];
    const float* kern = (const float*)d_in[1];
    const float* reck = (const float*)d_in[2];
    const float* bias = (const float*)d_in[3];
    const float* w2   = (const float*)d_in[4];
    const float* b2   = (const float*)d_in[5];
    float* out = (float*)d_out;

    char* ws = (char*)d_ws;
    size_t off = 0;
    auto alloc = [&](size_t bytes) {
        char* p = ws + off;
        off += (bytes + 255) & ~(size_t)255;
        return p;
    };
    __bf16*   Wtp    = (__bf16*)alloc((size_t)4096 * KLSTM * 2);
    __bf16*   Wt2p   = (__bf16*)alloc((size_t)NPAD * 1024 * 2);
    __bf16*   xbf    = (__bf16*)alloc((size_t)BATCH * SEQ * FEAT * 2);
    __bf16*   h0     = (__bf16*)alloc((size_t)BATCH * UNITS * 2);
    __bf16*   h1     = (__bf16*)alloc((size_t)BATCH * UNITS * 2);
    float*    logits = (float*)alloc((size_t)BATCH * NPAD * 4);
    unsigned* barcnt = (unsigned*)alloc(256);
    if (off > ws_size) return;  // loud failure: output stays zero

    (void)hipMemsetAsync(h0, 0, (size_t)BATCH * UNITS * 2, stream);
    (void)hipMemsetAsync(barcnt, 0, 256, stream);

    convert_x_kernel<<<(BATCH * SEQ * FEAT / 4 + 255) / 256, 256, 0, stream>>>(x, xbf);
    convert_weights_kernel<<<(4096 * KLSTM + 255) / 256, 256, 0, stream>>>(kern, reck, Wtp);
    convert_w2_kernel<<<(NPAD * 1024 + 255) / 256, 256, 0, stream>>>(w2, Wt2p);

    // one persistent dispatch for all SEQ steps; final h lands in h1 (SEQ odd)
    lstm_seq_kernel<<<dim3(16, 16), 512, 0, stream>>>(xbf, Wtp, bias, h0, h1, barcnt);

    dense_kernel<<<dim3(32, 5), 256, 0, stream>>>(h1, Wt2p, logits);
    softmax_kernel<<<BATCH, 256, 0, stream>>>(logits, b2, out);
}

// Round 4
// 3273.057 us; speedup vs baseline: 2.4306x; 1.3398x over previous
//
#include <hip/hip_runtime.h>

#define SEQ    59
#define FEAT   64
#define VOCAB  578
#define BATCH  4096
#define UNITS  1024
#define KLSTM  1088   // FEAT + UNITS; 17 K-tiles of 64, no padding
#define NPAD   640    // VOCAB padded to 5*128
#define NBLK   256    // grid blocks == CUs; 128KiB LDS forces 1 block/CU => all co-resident

typedef __bf16 bf16x8 __attribute__((ext_vector_type(8)));
typedef __bf16 bf16x4 __attribute__((ext_vector_type(4)));
typedef float  floatx4 __attribute__((ext_vector_type(4)));

typedef const __attribute__((address_space(1))) char gas_char;
typedef __attribute__((address_space(3))) char las_char;

__device__ __forceinline__ float sigmoid_f(float x) { return 1.f / (1.f + __expf(-x)); }
__device__ __forceinline__ float tanh_f(float x) { float e = __expf(2.f * x); return 1.f - 2.f / (e + 1.f); }

// normal (cacheable) staging: weights + x, read-only data
#define GLDS(srcp, dstp)  __builtin_amdgcn_global_load_lds((gas_char*)(srcp), (las_char*)(dstp), 16, 0, 0)
// device-coherent staging: h tiles. aux=0x11 = CPol SC0|SC1 (gfx940+): bypass XCD-local L2,
// read from the L3 coherence point where producers' sc0sc1 write-through stores land.
#define GLDSC(srcp, dstp) __builtin_amdgcn_global_load_lds((gas_char*)(srcp), (las_char*)(dstp), 16, 0, 0x11)
#define BAR()   __builtin_amdgcn_s_barrier()
#define LGKM0() asm volatile("s_waitcnt lgkmcnt(0)" ::: "memory")
#define VMW(n)  asm volatile("s_waitcnt vmcnt(" #n ")" ::: "memory")
#define MFMA    __builtin_amdgcn_mfma_f32_16x16x32_bf16

// ---------------- conversion kernels ----------------

__global__ void convert_x_kernel(const float* __restrict__ x, __bf16* __restrict__ xbf) {
    int i = blockIdx.x * 256 + threadIdx.x;
    const int total = BATCH * SEQ * FEAT / 4;
    if (i >= total) return;
    float4 v = ((const float4*)x)[i];
    bf16x4 o;
    o.x = (__bf16)v.x; o.y = (__bf16)v.y; o.z = (__bf16)v.z; o.w = (__bf16)v.w;
    ((bf16x4*)xbf)[i] = o;
}

// Wtp [4096 rows][KLSTM k] bf16 row-major.
// row np = bc*256 + w*64 + g*16 + j  ->  gate g of unit u = bc*64 + w*16 + j
__global__ void convert_weights_kernel(const float* __restrict__ kern,
                                       const float* __restrict__ reck,
                                       __bf16* __restrict__ Wtp) {
    int idx = blockIdx.x * 256 + threadIdx.x;
    if (idx >= 4096 * KLSTM) return;
    int np = idx / KLSTM;
    int k  = idx - np * KLSTM;
    int bc = np >> 8;
    int w  = (np >> 6) & 3;
    int g  = (np >> 4) & 3;
    int j  = np & 15;
    int n  = g * 1024 + bc * 64 + w * 16 + j;
    float v = (k < FEAT) ? kern[(size_t)k * 4096 + n]
                         : reck[(size_t)(k - FEAT) * 4096 + n];
    Wtp[idx] = (__bf16)v;
}

__global__ void convert_w2_kernel(const float* __restrict__ w2, __bf16* __restrict__ Wt2p) {
    int idx = blockIdx.x * 256 + threadIdx.x;
    if (idx >= NPAD * 1024) return;
    int n = idx >> 10;
    int k = idx & 1023;
    float v = (n < VOCAB) ? w2[(size_t)k * VOCAB + n] : 0.f;
    Wt2p[idx] = (__bf16)v;
}

// ---------------- persistent LSTM: all 59 steps in one kernel ----------------
// Same K-loop schedule/coherence as the (passed) round-3 kernel. Changes:
//  - epilogue: gates -> LDS transpose -> coalesced full-line global_store_dwordx4
//    sc0 sc1 (kills 2B write-through amplification: 32 scalar stores -> 4 vector)
//  - sync: per-rb GROUP barrier (16 blocks sharing batch rows rb), not grid-wide.
//    Groups are independent -> no straggler coupling; skew absorbs L3 latency.
__global__ void __launch_bounds__(512, 2) lstm_seq_kernel(
    const __bf16* __restrict__ xbf,
    const __bf16* __restrict__ Wtp,
    const float*  __restrict__ bias,
    __bf16*       __restrict__ hb0,
    __bf16*       __restrict__ hb1,
    unsigned*                  barGrp)   // 16 counters, 128B apart
{
    __shared__ __bf16 Ash[2][2][256 * 32];  // [buf][kh]  64 KiB
    __shared__ __bf16 Bsh[2][2][128 * 64];  // [buf][nh]  64 KiB

    const int tid  = threadIdx.x;
    const int wid  = tid >> 6;
    const int lane = tid & 63;
    const int ln   = lane & 15;
    const int lk   = lane >> 4;
    const int wm   = wid >> 2;
    const int wn   = wid & 3;
    const int bc   = blockIdx.x;   // weight block on x => XCD = bc&7: weights stay L2-local
    const int rb   = blockIdx.y;

    // ---- staging slot maps ----
    const int af0 = tid, af1 = 512 + tid;
    const int ar0 = af0 >> 2, ar1 = af1 >> 2;
    const int ac0 = (af0 & 3) ^ ((ar0 >> 1) & 3);
    const int ac1 = (af1 & 3) ^ ((ar1 >> 1) & 3);
    const int br0 = af0 >> 3, br1 = af1 >> 3;
    const int bq0 = (af0 & 7) ^ (br0 & 7);
    const int bq1 = (af1 & 7) ^ (br1 & 7);

    const __bf16* wB0 = Wtp + (size_t)(bc * 256 + br0) * KLSTM + bq0 * 8;
    const __bf16* wB1 = Wtp + (size_t)(bc * 256 + br1) * KLSTM + bq1 * 8;
    const __bf16* xr0 = xbf + (size_t)(rb * 256 + ar0) * (SEQ * FEAT) + ac0 * 8;
    const __bf16* xr1 = xbf + (size_t)(rb * 256 + ar1) * (SEQ * FEAT) + ac1 * 8;
    const size_t  ho0 = (size_t)(rb * 256 + ar0) * UNITS + ac0 * 8;
    const size_t  ho1 = (size_t)(rb * 256 + ar1) * UNITS + ac1 * 8;

    const int adst0 = wid << 9;
    const int adst1 = 4096 + (wid << 9);

    // ---- read offsets ----
    int offA[8];
#pragma unroll
    for (int m = 0; m < 8; ++m) {
        int row = wm * 128 + m * 16 + ln;
        offA[m] = row * 32 + ((lk ^ ((row >> 1) & 3)) << 3);
    }
    int offB[4][2];
#pragma unroll
    for (int g = 0; g < 4; ++g) {
        int nr = (wn & 1) * 64 + g * 16 + ln;
#pragma unroll
        for (int kk = 0; kk < 2; ++kk)
            offB[g][kk] = nr * 64 + ((((kk << 2) + lk) ^ (nr & 7)) << 3);
    }
    const int nhsel = wn >> 1;
    const __bf16* B0  = Bsh[0][nhsel];
    const __bf16* B1  = Bsh[1][nhsel];
    const __bf16* A00 = Ash[0][0];
    const __bf16* A01 = Ash[0][1];
    const __bf16* A10 = Ash[1][0];
    const __bf16* A11 = Ash[1][1];

    const int u = bc * 64 + wn * 16 + ln;
    const float bi  = bias[u];
    const float bfv = bias[UNITS + u];
    const float bg  = bias[2 * UNITS + u];
    const float bo  = bias[3 * UNITS + u];

    unsigned* grpCnt = barGrp + rb * 32;   // 128B-padded per-group counter

    float cc[8][4];
#pragma unroll
    for (int m = 0; m < 8; ++m)
#pragma unroll
        for (int r = 0; r < 4; ++r) cc[m][r] = 0.f;

    floatx4 acc[8][4];

#define STAH(BUF, KH, T) do { const int _c = ((T) - 1) * 64 + (KH) * 32; \
    GLDSC(hA0 + _c, &Ash[BUF][KH][adst0]); \
    GLDSC(hA1 + _c, &Ash[BUF][KH][adst1]); } while (0)
#define STBT(BUF, NH, T) do { const size_t _c = (size_t)(NH) * 128 * KLSTM + (T) * 64; \
    GLDS(wB0 + _c, &Bsh[BUF][NH][adst0]); \
    GLDS(wB1 + _c, &Bsh[BUF][NH][adst1]); } while (0)
#define PHASE_MFMA(MB, KKB) \
    __builtin_amdgcn_s_setprio(1); \
    _Pragma("unroll") \
    for (int m = 0; m < 4; ++m) \
    _Pragma("unroll") \
        for (int g = 0; g < 4; ++g) \
            acc[(MB) + m][g] = MFMA(aa[m], bb[KKB][g], acc[(MB) + m][g], 0, 0, 0); \
    __builtin_amdgcn_s_setprio(0)

#pragma unroll 1
    for (int t = 0; t < SEQ; ++t) {
        const __bf16* hin  = (t & 1) ? hb1 : hb0;
        __bf16*       hout = (t & 1) ? hb0 : hb1;
        const __bf16* hA0  = hin + ho0;
        const __bf16* hA1  = hin + ho1;
        const __bf16* xA0  = xr0 + t * FEAT;
        const __bf16* xA1  = xr1 + t * FEAT;

#pragma unroll
        for (int m = 0; m < 8; ++m)
#pragma unroll
            for (int g = 0; g < 4; ++g)
                acc[m][g] = (floatx4){0.f, 0.f, 0.f, 0.f};

        // ---- pre-barrier staging (h-independent): tile0 (x A + B), tile1 B ----
        STBT(0, 1, 0);
        GLDS(xA0, &Ash[0][0][adst0]); GLDS(xA1, &Ash[0][0][adst1]);
        STBT(0, 0, 0);
        GLDS(xA0 + 32, &Ash[0][1][adst0]); GLDS(xA1 + 32, &Ash[0][1][adst1]);
        STBT(1, 1, 1);
        STBT(1, 0, 1);

        // ---- GROUP barrier: only the 16 blocks sharing rows rb must rendezvous.
        // release = vmcnt(0) on last step's sc0sc1 write-through h stores.
        VMW(0);
        __syncthreads();
        if (tid == 0) {
            __hip_atomic_fetch_add(grpCnt, 1u, __ATOMIC_RELAXED, __HIP_MEMORY_SCOPE_AGENT);
            const unsigned tgt = (unsigned)(t + 1) * 16u;
            while (__hip_atomic_load(grpCnt, __ATOMIC_RELAXED, __HIP_MEMORY_SCOPE_AGENT) < tgt)
                __builtin_amdgcn_s_sleep(2);
        }
        __syncthreads();

        // ---- post-barrier: tile1 A (h cols 0..63), L2-bypassing coherent loads ----
        STAH(1, 0, 1);
        STAH(1, 1, 1);
        VMW(8);                      // tile0 already resident (drained above)
        BAR();
        // ---- tile0 compute (x @ W_x), from buf0 ----
        {
            bf16x8 bb[2][4], aa[4];
#pragma unroll
            for (int g = 0; g < 4; ++g) {
                bb[0][g] = *(const bf16x8*)(B0 + offB[g][0]);
                bb[1][g] = *(const bf16x8*)(B0 + offB[g][1]);
            }
#pragma unroll
            for (int m = 0; m < 4; ++m) aa[m] = *(const bf16x8*)(A00 + offA[m]);
            LGKM0(); PHASE_MFMA(0, 0);
#pragma unroll
            for (int m = 0; m < 4; ++m) aa[m] = *(const bf16x8*)(A00 + offA[4 + m]);
            LGKM0(); PHASE_MFMA(4, 0);
#pragma unroll
            for (int m = 0; m < 4; ++m) aa[m] = *(const bf16x8*)(A01 + offA[m]);
            LGKM0(); PHASE_MFMA(0, 1);
#pragma unroll
            for (int m = 0; m < 4; ++m) aa[m] = *(const bf16x8*)(A01 + offA[4 + m]);
            LGKM0(); PHASE_MFMA(4, 1);
        }
        BAR();
        // stage tile2 into buf0 (order mimics steady P5,P6,P7)
        STBT(0, 1, 2);
        STAH(0, 0, 2);
        STBT(0, 0, 2);
        VMW(6);                      // tile1 B+A fully landed; 6 tile2 loads in flight
        BAR();

        // ---- main loop: tiles 1..16, T1=2it+1 (buf1, P0-P3), T2=2it+2 (buf0, P4-P7) ----
#pragma unroll 1
        for (int it = 0; it < 8; ++it) {
            const int T2 = 2 * it + 2;
            const int T3 = (2 * it + 3 < 17) ? (2 * it + 3) : 16;  // clamped re-stage keeps
            const int T4 = (2 * it + 4 < 17) ? (2 * it + 4) : 16;  // vmcnt accounting exact
            bf16x8 bb[2][4], aa[4];
            // P0
#pragma unroll
            for (int g = 0; g < 4; ++g) {
                bb[0][g] = *(const bf16x8*)(B1 + offB[g][0]);
                bb[1][g] = *(const bf16x8*)(B1 + offB[g][1]);
            }
#pragma unroll
            for (int m = 0; m < 4; ++m) aa[m] = *(const bf16x8*)(A10 + offA[m]);
            STAH(0, 1, T2);
            BAR(); LGKM0(); PHASE_MFMA(0, 0); BAR();
            // P1
#pragma unroll
            for (int m = 0; m < 4; ++m) aa[m] = *(const bf16x8*)(A10 + offA[4 + m]);
            STBT(1, 1, T3);
            BAR(); LGKM0(); PHASE_MFMA(4, 0); BAR();
            // P2
#pragma unroll
            for (int m = 0; m < 4; ++m) aa[m] = *(const bf16x8*)(A11 + offA[m]);
            STAH(1, 0, T3);
            BAR(); LGKM0(); PHASE_MFMA(0, 1); BAR();
            // P3
#pragma unroll
            for (int m = 0; m < 4; ++m) aa[m] = *(const bf16x8*)(A11 + offA[4 + m]);
            STBT(1, 0, T3);
            BAR(); LGKM0(); PHASE_MFMA(4, 1); VMW(6); BAR();
            // P4
#pragma unroll
            for (int g = 0; g < 4; ++g) {
                bb[0][g] = *(const bf16x8*)(B0 + offB[g][0]);
                bb[1][g] = *(const bf16x8*)(B0 + offB[g][1]);
            }
#pragma unroll
            for (int m = 0; m < 4; ++m) aa[m] = *(const bf16x8*)(A00 + offA[m]);
            STAH(1, 1, T3);
            BAR(); LGKM0(); PHASE_MFMA(0, 0); BAR();
            // P5
#pragma unroll
            for (int m = 0; m < 4; ++m) aa[m] = *(const bf16x8*)(A00 + offA[4 + m]);
            STBT(0, 1, T4);
            BAR(); LGKM0(); PHASE_MFMA(4, 0); BAR();
            // P6
#pragma unroll
            for (int m = 0; m < 4; ++m) aa[m] = *(const bf16x8*)(A01 + offA[m]);
            STAH(0, 0, T4);
            BAR(); LGKM0(); PHASE_MFMA(0, 1); BAR();
            // P7
#pragma unroll
            for (int m = 0; m < 4; ++m) aa[m] = *(const bf16x8*)(A01 + offA[4 + m]);
            STBT(0, 0, T4);
            BAR(); LGKM0(); PHASE_MFMA(4, 1); VMW(6); BAR();
        }
        VMW(0);   // drain clamped tail stages before LDS is reused below

        // ---- fused LSTM epilogue: c in registers; h -> LDS transpose -> coalesced
        //      full-line sc0sc1 stores (128B line = 8 lanes x dwordx4) ----
        {
            __bf16* h_lds = &Ash[0][0][0];          // 256 x 64 bf16 = 32 KiB (dead region)
            const int ul = wn * 16 + ln;
#pragma unroll
            for (int m = 0; m < 8; ++m) {
                const int lr0 = wm * 128 + m * 16 + lk * 4;
#pragma unroll
                for (int r = 0; r < 4; ++r) {
                    float ig = sigmoid_f(acc[m][0][r] + bi);
                    float fg = sigmoid_f(acc[m][1][r] + bfv);
                    float gg = tanh_f(acc[m][2][r] + bg);
                    float og = sigmoid_f(acc[m][3][r] + bo);
                    float cn = fg * cc[m][r] + ig * gg;
                    cc[m][r] = cn;
                    h_lds[(lr0 + r) * 64 + ul] = (__bf16)(og * tanh_f(cn));
                }
            }
            BAR();
#pragma unroll
            for (int j = 0; j < 4; ++j) {
                const int chunk = j * 512 + tid;     // 16B chunk id, lanes consecutive
                const int lrow  = chunk >> 3;
                const int cof   = (chunk & 7) * 8;   // elem offset within 128B row slice
                floatx4 v = *(const floatx4*)(h_lds + lrow * 64 + cof);
                const __bf16* hp = hout + (size_t)(rb * 256 + lrow) * UNITS + bc * 64 + cof;
                asm volatile("global_store_dwordx4 %0, %1, off sc0 sc1"
                             :: "v"(hp), "v"(v) : "memory");
            }
            BAR();   // all waves done reading h_lds before next-iter staging reuses Ash[0]
        }
    }
    VMW(0);   // final h stores visible before kernel end
#undef STAH
#undef STBT
}

// ---------------- final dense: [4096,1024] @ [1024,640] -> logits fp32 ----------------
__global__ void __launch_bounds__(256) dense_kernel(
    const __bf16* __restrict__ hin,
    const __bf16* __restrict__ Wt2p,
    float*        __restrict__ logits)
{
    __shared__ __bf16 As[128 * 64];
    __shared__ __bf16 Bs[128 * 64];

    const int tid  = threadIdx.x;
    const int wid  = tid >> 6;
    const int lane = tid & 63;
    const int ln   = lane & 15;
    const int lk   = lane >> 4;
    const int wm   = wid >> 1;
    const int wn   = wid & 1;
    const int rb   = blockIdx.x;
    const int nb   = blockIdx.y;

    floatx4 acc[4][4];
#pragma unroll
    for (int m = 0; m < 4; ++m)
#pragma unroll
        for (int g = 0; g < 4; ++g)
            acc[m][g] = (floatx4){0.f, 0.f, 0.f, 0.f};

    int s_row[4], s_kgd[4];
#pragma unroll
    for (int q = 0; q < 4; ++q) {
        int flat = q * 256 + tid;
        int row  = flat >> 3;
        s_row[q] = row;
        s_kgd[q] = (flat & 7) ^ (row & 7);
    }

    for (int kt = 0; kt < 16; ++kt) {
        __syncthreads();
#pragma unroll
        for (int q = 0; q < 4; ++q) {
            const int row = s_row[q], kgd = s_kgd[q];
            const __bf16* gp = hin + ((size_t)(rb * 128 + row) << 10) + kt * 64 + kgd * 8;
            GLDS(gp, As + (size_t)(q * 256 + (wid << 6)) * 8);
        }
#pragma unroll
        for (int q = 0; q < 4; ++q) {
            const int n = s_row[q], kgd = s_kgd[q];
            const __bf16* gp = Wt2p + ((size_t)(nb * 128 + n) << 10) + kt * 64 + kgd * 8;
            GLDS(gp, Bs + (size_t)(q * 256 + (wid << 6)) * 8);
        }
        __syncthreads();
#pragma unroll
        for (int kk = 0; kk < 2; ++kk) {
            const int kg = kk * 4 + lk;
            bf16x8 a[4], b[4];
#pragma unroll
            for (int m = 0; m < 4; ++m) {
                int row  = wm * 64 + m * 16 + ln;
                int ccol = (kg ^ (row & 7)) * 8;
                a[m] = *(const bf16x8*)(As + row * 64 + ccol);
            }
#pragma unroll
            for (int g = 0; g < 4; ++g) {
                int n    = g * 32 + wn * 16 + ln;
                int ccol = (kg ^ (n & 7)) * 8;
                b[g] = *(const bf16x8*)(Bs + n * 64 + ccol);
            }
#pragma unroll
            for (int m = 0; m < 4; ++m)
#pragma unroll
                for (int g = 0; g < 4; ++g)
                    acc[m][g] = MFMA(a[m], b[g], acc[m][g], 0, 0, 0);
        }
    }

#pragma unroll
    for (int m = 0; m < 4; ++m) {
        const int row0 = rb * 128 + wm * 64 + m * 16 + lk * 4;
#pragma unroll
        for (int g = 0; g < 4; ++g) {
            const int n = nb * 128 + g * 32 + wn * 16 + ln;
#pragma unroll
            for (int r = 0; r < 4; ++r)
                logits[(size_t)(row0 + r) * NPAD + n] = acc[m][g][r];
        }
    }
}

// ---------------- row softmax over 578 cols (+b2) ----------------
__global__ void __launch_bounds__(256) softmax_kernel(
    const float* __restrict__ logits,
    const float* __restrict__ b2,
    float* __restrict__ out)
{
    const int row = blockIdx.x;
    const int tid = threadIdx.x;
    __shared__ float red[8];

    float z[3];
    float lmax = -1e30f;
#pragma unroll
    for (int j = 0; j < 3; ++j) {
        int col = tid + j * 256;
        if (col < VOCAB) {
            z[j] = logits[(size_t)row * NPAD + col] + b2[col];
            lmax = fmaxf(lmax, z[j]);
        } else z[j] = -1e30f;
    }
    for (int off = 32; off > 0; off >>= 1) lmax = fmaxf(lmax, __shfl_xor(lmax, off));
    if ((tid & 63) == 0) red[tid >> 6] = lmax;
    __syncthreads();
    lmax = fmaxf(fmaxf(red[0], red[1]), fmaxf(red[2], red[3]));
    __syncthreads();

    float lsum = 0.f;
#pragma unroll
    for (int j = 0; j < 3; ++j) {
        int col = tid + j * 256;
        if (col < VOCAB) { z[j] = __expf(z[j] - lmax); lsum += z[j]; }
    }
    for (int off = 32; off > 0; off >>= 1) lsum += __shfl_xor(lsum, off);
    if ((tid & 63) == 0) red[tid >> 6] = lsum;
    __syncthreads();
    lsum = red[0] + red[1] + red[2] + red[3];
    float inv = 1.f / lsum;
#pragma unroll
    for (int j = 0; j < 3; ++j) {
        int col = tid + j * 256;
        if (col < VOCAB) out[(size_t)row * VOCAB + col] = z[j] * inv;
    }
}

// ---------------- launch ----------------
extern "C" void kernel_launch(void* const* d_in, const int* in_sizes, int n_in,
                              void* d_out, int out_size, void* d_ws, size_t ws_size,
                              hipStream_t stream)
{
    const float* x    = (const float*)d_in[0];
    const float* kern = (const float*)d_in[1];
    const float* reck = (const float*)d_in[2];
    const float* bias = (const float*)d_in[3];
    const float* w2   = (const float*)d_in[4];
    const float* b2   = (const float*)d_in[5];
    float* out = (float*)d_out;

    char* ws = (char*)d_ws;
    size_t off = 0;
    auto alloc = [&](size_t bytes) {
        char* p = ws + off;
        off += (bytes + 255) & ~(size_t)255;
        return p;
    };
    __bf16*   Wtp    = (__bf16*)alloc((size_t)4096 * KLSTM * 2);
    __bf16*   Wt2p   = (__bf16*)alloc((size_t)NPAD * 1024 * 2);
    __bf16*   xbf    = (__bf16*)alloc((size_t)BATCH * SEQ * FEAT * 2);
    __bf16*   h0     = (__bf16*)alloc((size_t)BATCH * UNITS * 2);
    __bf16*   h1     = (__bf16*)alloc((size_t)BATCH * UNITS * 2);
    float*    logits = (float*)alloc((size_t)BATCH * NPAD * 4);
    unsigned* barGrp = (unsigned*)alloc(16 * 128);
    if (off > ws_size) return;  // loud failure: output stays zero

    (void)hipMemsetAsync(h0, 0, (size_t)BATCH * UNITS * 2, stream);
    (void)hipMemsetAsync(barGrp, 0, 16 * 128, stream);

    convert_x_kernel<<<(BATCH * SEQ * FEAT / 4 + 255) / 256, 256, 0, stream>>>(x, xbf);
    convert_weights_kernel<<<(4096 * KLSTM + 255) / 256, 256, 0, stream>>>(kern, reck, Wtp);
    convert_w2_kernel<<<(NPAD * 1024 + 255) / 256, 256, 0, stream>>>(w2, Wt2p);

    // one persistent dispatch for all SEQ steps; final h lands in h1 (SEQ odd)
    lstm_seq_kernel<<<dim3(16, 16), 512, 0, stream>>>(xbf, Wtp, bias, h0, h1, barGrp);

    dense_kernel<<<dim3(32, 5), 256, 0, stream>>>(h1, Wt2p, logits);
    softmax_kernel<<<BATCH, 256, 0, stream>>>(logits, b2, out);
}

// Round 6
// 3048.038 us; speedup vs baseline: 2.6100x; 1.0738x over previous
//
#include <hip/hip_runtime.h>

#define SEQ    59
#define FEAT   64
#define VOCAB  578
#define BATCH  4096
#define UNITS  1024
#define KLSTM  1088   // FEAT + UNITS; 17 K-tiles of 64
#define NPAD   640    // VOCAB padded to 5*128

typedef __bf16 bf16x8 __attribute__((ext_vector_type(8)));
typedef __bf16 bf16x4 __attribute__((ext_vector_type(4)));
typedef float  floatx4 __attribute__((ext_vector_type(4)));

typedef const __attribute__((address_space(1))) char gas_char;
typedef __attribute__((address_space(3))) char las_char;

__device__ __forceinline__ float sigmoid_f(float x) { return 1.f / (1.f + __expf(-x)); }
__device__ __forceinline__ float tanh_f(float x) { float e = __expf(2.f * x); return 1.f - 2.f / (e + 1.f); }

// cacheable staging (weights, x)
#define GLDS(srcp, dstp)  __builtin_amdgcn_global_load_lds((gas_char*)(srcp), (las_char*)(dstp), 16, 0, 0)
// device-coherent staging (h): aux=0x11 = SC0|SC1 -> bypass XCD-local L2, read L3 coherence point
#define GLDSC(srcp, dstp) __builtin_amdgcn_global_load_lds((gas_char*)(srcp), (las_char*)(dstp), 16, 0, 0x11)
#define VMW(n)  asm volatile("s_waitcnt vmcnt(" #n ")" ::: "memory")
#define MFMA    __builtin_amdgcn_mfma_f32_16x16x32_bf16

// ---------------- conversion kernels ----------------

__global__ void convert_x_kernel(const float* __restrict__ x, __bf16* __restrict__ xbf) {
    int i = blockIdx.x * 256 + threadIdx.x;
    const int total = BATCH * SEQ * FEAT / 4;
    if (i >= total) return;
    float4 v = ((const float4*)x)[i];
    bf16x4 o;
    o.x = (__bf16)v.x; o.y = (__bf16)v.y; o.z = (__bf16)v.z; o.w = (__bf16)v.w;
    ((bf16x4*)xbf)[i] = o;
}

// Round-0 proven layout: Wtp [4096 rows][1088 k]; row np = ublk*128 + gate*32 + j
// -> weight col n = gate*1024 + ublk*32 + j
__global__ void convert_weights_kernel(const float* __restrict__ kern,
                                       const float* __restrict__ reck,
                                       __bf16* __restrict__ Wtp) {
    int idx = blockIdx.x * 256 + threadIdx.x;
    if (idx >= 4096 * KLSTM) return;
    int np = idx / KLSTM;
    int k  = idx - np * KLSTM;
    int ublk = np >> 7;
    int g    = (np >> 5) & 3;
    int j    = np & 31;
    int n    = g * 1024 + ublk * 32 + j;
    float v = (k < FEAT) ? kern[(size_t)k * 4096 + n]
                         : reck[(size_t)(k - FEAT) * 4096 + n];
    Wtp[idx] = (__bf16)v;
}

__global__ void convert_w2_kernel(const float* __restrict__ w2, __bf16* __restrict__ Wt2p) {
    int idx = blockIdx.x * 256 + threadIdx.x;
    if (idx >= NPAD * 1024) return;
    int n = idx >> 10;
    int k = idx & 1023;
    float v = (n < VOCAB) ? w2[(size_t)k * VOCAB + n] : 0.f;
    Wt2p[idx] = (__bf16)v;
}

// ---------------- persistent LSTM: round-0 2-block/CU core, 59 steps in-kernel ----------------
// Block (yb, rb): 128 batch rows (rb) x 64 units (yb) via two 128-col B tiles.
// 4 waves, 48KiB LDS, launch_bounds(256,2) -> 2 blocks/CU; grid 512 launched
// COOPERATIVELY so co-residency is validated by the runtime, not assumed.
// c-state in registers. h coherence: sc0sc1 write-through stores + aux=0x11 loads +
// per-rb group barrier (16 blocks), release = VMW(0) (round-3/4 proven protocol).
// Grid (16,32): XCD = yb%8 -> per-XCD weight set 1.1MB, L2-resident all 59 steps.
__global__ void __launch_bounds__(256, 2) lstm_seq_kernel(
    const __bf16* __restrict__ xbf,
    const __bf16* __restrict__ Wtp,
    const float*  __restrict__ bias,
    __bf16*       __restrict__ hb0,
    __bf16*       __restrict__ hb1,
    unsigned*                  barGrp)   // 32 counters, 128B apart
{
    __shared__ __bf16 As[128 * 64];      // 16 KiB (reused as h_lds in epilogue)
    __shared__ __bf16 Bs[2][128 * 64];   // 32 KiB

    const int tid  = threadIdx.x;
    const int wid  = tid >> 6;
    const int lane = tid & 63;
    const int ln   = lane & 15;
    const int lk   = lane >> 4;
    const int wm   = wid >> 1;
    const int wn   = wid & 1;
    const int yb   = blockIdx.x;   // unit block -> XCD = yb%8 (weights L2-local)
    const int rb   = blockIdx.y;   // batch block (128 rows)

    // staging slot map (round-0): 128 rows x 8 chunks, swizzle c ^= row&7
    int s_row[4], s_kgd[4];
#pragma unroll
    for (int q = 0; q < 4; ++q) {
        int flat = q * 256 + tid;
        int row  = flat >> 3;
        s_row[q] = row;
        s_kgd[q] = (flat & 7) ^ (row & 7);
    }

    unsigned* grpCnt = barGrp + rb * 32;   // 128B-padded per-group counter

    // bias for the two owned unit sub-blocks (p=0,1)
    float BI[2], BF_[2], BG[2], BO[2];
#pragma unroll
    for (int p = 0; p < 2; ++p) {
        const int u = yb * 64 + p * 32 + wn * 16 + ln;
        BI[p]  = bias[u];
        BF_[p] = bias[UNITS + u];
        BG[p]  = bias[2 * UNITS + u];
        BO[p]  = bias[3 * UNITS + u];
    }

    float cc[2][4][4];
#pragma unroll
    for (int p = 0; p < 2; ++p)
#pragma unroll
        for (int m = 0; m < 4; ++m)
#pragma unroll
            for (int r = 0; r < 4; ++r) cc[p][m][r] = 0.f;

    floatx4 acc[2][4][4];

    auto compute_tile = [&]() {
#pragma unroll
        for (int kk = 0; kk < 2; ++kk) {
            const int kg = kk * 4 + lk;
            bf16x8 a[4], b0[4], b1[4];
#pragma unroll
            for (int m = 0; m < 4; ++m) {
                int row  = wm * 64 + m * 16 + ln;
                int ccol = (kg ^ (row & 7)) * 8;
                a[m] = *(const bf16x8*)(As + row * 64 + ccol);
            }
#pragma unroll
            for (int g = 0; g < 4; ++g) {
                int n    = g * 32 + wn * 16 + ln;
                int ccol = (kg ^ (n & 7)) * 8;
                b0[g] = *(const bf16x8*)(Bs[0] + n * 64 + ccol);
                b1[g] = *(const bf16x8*)(Bs[1] + n * 64 + ccol);
            }
#pragma unroll
            for (int m = 0; m < 4; ++m)
#pragma unroll
                for (int g = 0; g < 4; ++g) {
                    acc[0][m][g] = MFMA(a[m], b0[g], acc[0][m][g], 0, 0, 0);
                    acc[1][m][g] = MFMA(a[m], b1[g], acc[1][m][g], 0, 0, 0);
                }
        }
    };

#define STAGE_B(KT) do { \
    _Pragma("unroll") \
    for (int p = 0; p < 2; ++p) \
    _Pragma("unroll") \
    for (int q = 0; q < 4; ++q) { \
        const __bf16* gp = Wtp + (size_t)(yb * 256 + p * 128 + s_row[q]) * KLSTM + (KT) * 64 + s_kgd[q] * 8; \
        GLDS(gp, Bs[p] + (size_t)(q * 256 + (wid << 6)) * 8); \
    } } while (0)

#pragma unroll 1
    for (int t = 0; t < SEQ; ++t) {
        const __bf16* hin  = (t & 1) ? hb1 : hb0;
        __bf16*       hout = (t & 1) ? hb0 : hb1;

#pragma unroll
        for (int p = 0; p < 2; ++p)
#pragma unroll
            for (int m = 0; m < 4; ++m)
#pragma unroll
                for (int g = 0; g < 4; ++g)
                    acc[p][m][g] = (floatx4){0.f, 0.f, 0.f, 0.f};

        // ---- hoisted kt=0 stage (h-independent): A from x(t), B tiles kt=0 ----
#pragma unroll
        for (int q = 0; q < 4; ++q) {
            const __bf16* gp = xbf + (size_t)(rb * 128 + s_row[q]) * (SEQ * FEAT) + t * FEAT + s_kgd[q] * 8;
            GLDS(gp, As + (size_t)(q * 256 + (wid << 6)) * 8);
        }
        STAGE_B(0);

        // ---- group barrier: wait for all 16 producers of h(t-1) rows rb.
        // Bounded spin: a true deadlock degrades to a loud wrong answer, not a hang.
        if (tid == 0) {
            const unsigned tgt = (unsigned)t * 16u;
            unsigned spin = 0;
            while (__hip_atomic_load(grpCnt, __ATOMIC_RELAXED, __HIP_MEMORY_SCOPE_AGENT) < tgt) {
                __builtin_amdgcn_s_sleep(2);
                if (++spin > (1u << 22)) break;   // ~0.2s escape hatch
            }
        }
        __syncthreads();   // drains vmcnt -> kt0 resident; all threads past barrier wait

        compute_tile();    // kt = 0 (x @ W_x)

        // ---- K-loop tiles 1..16 (h @ W_h), round-0 2-phase structure ----
        for (int kt = 1; kt < 17; ++kt) {
            __syncthreads();
#pragma unroll
            for (int q = 0; q < 4; ++q) {
                const __bf16* gp = hin + ((size_t)(rb * 128 + s_row[q]) << 10) + (kt - 1) * 64 + s_kgd[q] * 8;
                GLDSC(gp, As + (size_t)(q * 256 + (wid << 6)) * 8);
            }
            STAGE_B(kt);
            __syncthreads();
            compute_tile();
        }

        // ---- epilogue: c in regs; h -> swizzled LDS -> coalesced sc0sc1 lines ----
        __syncthreads();                 // all waves done reading As (last tile)
        {
            __bf16* h_lds = As;          // 128 x 64 bf16, XOR-swizzled cols
#pragma unroll
            for (int p = 0; p < 2; ++p) {
                const int cl = (p * 32 + wn * 16 + ln) ^ (lk << 4);  // bank-conflict-free
#pragma unroll
                for (int m = 0; m < 4; ++m) {
                    const int r0 = wm * 64 + m * 16 + lk * 4;
#pragma unroll
                    for (int r = 0; r < 4; ++r) {
                        float ig = sigmoid_f(acc[p][m][0][r] + BI[p]);
                        float fg = sigmoid_f(acc[p][m][1][r] + BF_[p]);
                        float gg = tanh_f(acc[p][m][2][r] + BG[p]);
                        float og = sigmoid_f(acc[p][m][3][r] + BO[p]);
                        float cn = fg * cc[p][m][r] + ig * gg;
                        cc[p][m][r] = cn;
                        h_lds[(r0 + r) * 64 + cl] = (__bf16)(og * tanh_f(cn));
                    }
                }
            }
            __syncthreads();
#pragma unroll
            for (int j = 0; j < 4; ++j) {
                const int chunk = j * 256 + tid;          // 1024 16B-chunks
                const int lrow  = chunk >> 3;
                const int cof   = (chunk & 7) * 8;
                const int pcol  = cof ^ (((lrow >> 2) & 3) << 4);   // writer's lk == (row>>2)&3
                floatx4 v = *(const floatx4*)(h_lds + lrow * 64 + pcol);
                const __bf16* hp = hout + (size_t)(rb * 128 + lrow) * UNITS + yb * 64 + cof;
                asm volatile("global_store_dwordx4 %0, %1, off sc0 sc1"
                             :: "v"(hp), "v"(v) : "memory");
            }
            VMW(0);                      // this wave's h stores visible at L3
            __syncthreads();             // all waves drained + done reading h_lds
            if (tid == 0)
                __hip_atomic_fetch_add(grpCnt, 1u, __ATOMIC_RELAXED, __HIP_MEMORY_SCOPE_AGENT);
        }
    }
#undef STAGE_B
}

// ---------------- final dense: [4096,1024] @ [1024,640] -> logits fp32 ----------------
__global__ void __launch_bounds__(256) dense_kernel(
    const __bf16* __restrict__ hin,
    const __bf16* __restrict__ Wt2p,
    float*        __restrict__ logits)
{
    __shared__ __bf16 As[128 * 64];
    __shared__ __bf16 Bs[128 * 64];

    const int tid  = threadIdx.x;
    const int wid  = tid >> 6;
    const int lane = tid & 63;
    const int ln   = lane & 15;
    const int lk   = lane >> 4;
    const int wm   = wid >> 1;
    const int wn   = wid & 1;
    const int rb   = blockIdx.x;
    const int nb   = blockIdx.y;

    floatx4 acc[4][4];
#pragma unroll
    for (int m = 0; m < 4; ++m)
#pragma unroll
        for (int g = 0; g < 4; ++g)
            acc[m][g] = (floatx4){0.f, 0.f, 0.f, 0.f};

    int s_row[4], s_kgd[4];
#pragma unroll
    for (int q = 0; q < 4; ++q) {
        int flat = q * 256 + tid;
        int row  = flat >> 3;
        s_row[q] = row;
        s_kgd[q] = (flat & 7) ^ (row & 7);
    }

    for (int kt = 0; kt < 16; ++kt) {
        __syncthreads();
#pragma unroll
        for (int q = 0; q < 4; ++q) {
            const int row = s_row[q], kgd = s_kgd[q];
            const __bf16* gp = hin + ((size_t)(rb * 128 + row) << 10) + kt * 64 + kgd * 8;
            GLDS(gp, As + (size_t)(q * 256 + (wid << 6)) * 8);
        }
#pragma unroll
        for (int q = 0; q < 4; ++q) {
            const int n = s_row[q], kgd = s_kgd[q];
            const __bf16* gp = Wt2p + ((size_t)(nb * 128 + n) << 10) + kt * 64 + kgd * 8;
            GLDS(gp, Bs + (size_t)(q * 256 + (wid << 6)) * 8);
        }
        __syncthreads();
#pragma unroll
        for (int kk = 0; kk < 2; ++kk) {
            const int kg = kk * 4 + lk;
            bf16x8 a[4], b[4];
#pragma unroll
            for (int m = 0; m < 4; ++m) {
                int row  = wm * 64 + m * 16 + ln;
                int ccol = (kg ^ (row & 7)) * 8;
                a[m] = *(const bf16x8*)(As + row * 64 + ccol);
            }
#pragma unroll
            for (int g = 0; g < 4; ++g) {
                int n    = g * 32 + wn * 16 + ln;
                int ccol = (kg ^ (n & 7)) * 8;
                b[g] = *(const bf16x8*)(Bs + n * 64 + ccol);
            }
#pragma unroll
            for (int m = 0; m < 4; ++m)
#pragma unroll
                for (int g = 0; g < 4; ++g)
                    acc[m][g] = MFMA(a[m], b[g], acc[m][g], 0, 0, 0);
        }
    }

#pragma unroll
    for (int m = 0; m < 4; ++m) {
        const int row0 = rb * 128 + wm * 64 + m * 16 + lk * 4;
#pragma unroll
        for (int g = 0; g < 4; ++g) {
            const int n = nb * 128 + g * 32 + wn * 16 + ln;
#pragma unroll
            for (int r = 0; r < 4; ++r)
                logits[(size_t)(row0 + r) * NPAD + n] = acc[m][g][r];
        }
    }
}

// ---------------- row softmax over 578 cols (+b2) ----------------
__global__ void __launch_bounds__(256) softmax_kernel(
    const float* __restrict__ logits,
    const float* __restrict__ b2,
    float* __restrict__ out)
{
    const int row = blockIdx.x;
    const int tid = threadIdx.x;
    __shared__ float red[8];

    float z[3];
    float lmax = -1e30f;
#pragma unroll
    for (int j = 0; j < 3; ++j) {
        int col = tid + j * 256;
        if (col < VOCAB) {
            z[j] = logits[(size_t)row * NPAD + col] + b2[col];
            lmax = fmaxf(lmax, z[j]);
        } else z[j] = -1e30f;
    }
    for (int off = 32; off > 0; off >>= 1) lmax = fmaxf(lmax, __shfl_xor(lmax, off));
    if ((tid & 63) == 0) red[tid >> 6] = lmax;
    __syncthreads();
    lmax = fmaxf(fmaxf(red[0], red[1]), fmaxf(red[2], red[3]));
    __syncthreads();

    float lsum = 0.f;
#pragma unroll
    for (int j = 0; j < 3; ++j) {
        int col = tid + j * 256;
        if (col < VOCAB) { z[j] = __expf(z[j] - lmax); lsum += z[j]; }
    }
    for (int off = 32; off > 0; off >>= 1) lsum += __shfl_xor(lsum, off);
    if ((tid & 63) == 0) red[tid >> 6] = lsum;
    __syncthreads();
    lsum = red[0] + red[1] + red[2] + red[3];
    float inv = 1.f / lsum;
#pragma unroll
    for (int j = 0; j < 3; ++j) {
        int col = tid + j * 256;
        if (col < VOCAB) out[(size_t)row * VOCAB + col] = z[j] * inv;
    }
}

// ---------------- launch ----------------
extern "C" void kernel_launch(void* const* d_in, const int* in_sizes, int n_in,
                              void* d_out, int out_size, void* d_ws, size_t ws_size,
                              hipStream_t stream)
{
    const float* x    = (const float*)d_in[0];
    const float* kern = (const float*)d_in[1];
    const float* reck = (const float*)d_in[2];
    const float* bias = (const float*)d_in[3];
    const float* w2   = (const float*)d_in[4];
    const float* b2   = (const float*)d_in[5];
    float* out = (float*)d_out;

    char* ws = (char*)d_ws;
    size_t off = 0;
    auto alloc = [&](size_t bytes) {
        char* p = ws + off;
        off += (bytes + 255) & ~(size_t)255;
        return p;
    };
    __bf16*   Wtp    = (__bf16*)alloc((size_t)4096 * KLSTM * 2);
    __bf16*   Wt2p   = (__bf16*)alloc((size_t)NPAD * 1024 * 2);
    __bf16*   xbf    = (__bf16*)alloc((size_t)BATCH * SEQ * FEAT * 2);
    __bf16*   h0     = (__bf16*)alloc((size_t)BATCH * UNITS * 2);
    __bf16*   h1     = (__bf16*)alloc((size_t)BATCH * UNITS * 2);
    float*    logits = (float*)alloc((size_t)BATCH * NPAD * 4);
    unsigned* barGrp = (unsigned*)alloc(32 * 128);
    if (off > ws_size) return;  // loud failure: output stays zero

    (void)hipMemsetAsync(h0, 0, (size_t)BATCH * UNITS * 2, stream);
    (void)hipMemsetAsync(barGrp, 0, 32 * 128, stream);

    convert_x_kernel<<<(BATCH * SEQ * FEAT / 4 + 255) / 256, 256, 0, stream>>>(x, xbf);
    convert_weights_kernel<<<(4096 * KLSTM + 255) / 256, 256, 0, stream>>>(kern, reck, Wtp);
    convert_w2_kernel<<<(NPAD * 1024 + 255) / 256, 256, 0, stream>>>(w2, Wt2p);

    // one persistent dispatch for all SEQ steps; final h lands in h1 (SEQ odd).
    // Cooperative launch validates 2-block/CU co-residency (512 blocks on 256 CUs);
    // fall back to a plain launch if the runtime rejects cooperative here.
    {
        const __bf16* a0 = xbf; const __bf16* a1 = Wtp; const float* a2 = bias;
        __bf16* a3 = h0; __bf16* a4 = h1; unsigned* a5 = barGrp;
        void* args[6] = { (void*)&a0, (void*)&a1, (void*)&a2,
                          (void*)&a3, (void*)&a4, (void*)&a5 };
        hipError_t ce = hipLaunchCooperativeKernel((const void*)lstm_seq_kernel,
                                                   dim3(16, 32), dim3(256),
                                                   args, 0, stream);
        if (ce != hipSuccess)
            lstm_seq_kernel<<<dim3(16, 32), 256, 0, stream>>>(xbf, Wtp, bias, h0, h1, barGrp);
    }

    dense_kernel<<<dim3(32, 5), 256, 0, stream>>>(h1, Wt2p, logits);
    softmax_kernel<<<BATCH, 256, 0, stream>>>(logits, b2, out);
}

// Round 7
// 2740.664 us; speedup vs baseline: 2.9027x; 1.1122x over previous
//
#include <hip/hip_runtime.h>

#define SEQ    59
#define FEAT   64
#define VOCAB  578
#define BATCH  4096
#define UNITS  1024
#define KLSTM  1088   // FEAT + UNITS; 17 K-tiles of 64
#define NPAD   640    // VOCAB padded to 5*128

typedef __bf16 bf16x8 __attribute__((ext_vector_type(8)));
typedef __bf16 bf16x4 __attribute__((ext_vector_type(4)));
typedef float  floatx4 __attribute__((ext_vector_type(4)));

typedef const __attribute__((address_space(1))) char gas_char;
typedef __attribute__((address_space(3))) char las_char;

__device__ __forceinline__ float sigmoid_f(float x) { return 1.f / (1.f + __expf(-x)); }
__device__ __forceinline__ float tanh_f(float x) { float e = __expf(2.f * x); return 1.f - 2.f / (e + 1.f); }

#define GLDS(srcp, dstp) __builtin_amdgcn_global_load_lds((gas_char*)(srcp), (las_char*)(dstp), 16, 0, 0)
#define MFMA __builtin_amdgcn_mfma_f32_16x16x32_bf16

// ---------------- conversion kernels ----------------

__global__ void convert_x_kernel(const float* __restrict__ x, __bf16* __restrict__ xbf) {
    int i = blockIdx.x * 256 + threadIdx.x;
    const int total = BATCH * SEQ * FEAT / 4;
    if (i >= total) return;
    float4 v = ((const float4*)x)[i];
    bf16x4 o;
    o.x = (__bf16)v.x; o.y = (__bf16)v.y; o.z = (__bf16)v.z; o.w = (__bf16)v.w;
    ((bf16x4*)xbf)[i] = o;
}

// Wtp [4096 rows][1088 k] bf16 row-major; row np = ublk*128 + gate*32 + j
// -> weight col n = gate*1024 + ublk*32 + j  (round-0 proven layout)
__global__ void convert_weights_kernel(const float* __restrict__ kern,
                                       const float* __restrict__ reck,
                                       __bf16* __restrict__ Wtp) {
    int idx = blockIdx.x * 256 + threadIdx.x;
    if (idx >= 4096 * KLSTM) return;
    int np = idx / KLSTM;
    int k  = idx - np * KLSTM;
    int ublk = np >> 7;
    int g    = (np >> 5) & 3;
    int j    = np & 31;
    int n    = g * 1024 + ublk * 32 + j;
    float v = (k < FEAT) ? kern[(size_t)k * 4096 + n]
                         : reck[(size_t)(k - FEAT) * 4096 + n];
    Wtp[idx] = (__bf16)v;
}

__global__ void convert_w2_kernel(const float* __restrict__ w2, __bf16* __restrict__ Wt2p) {
    int idx = blockIdx.x * 256 + threadIdx.x;
    if (idx >= NPAD * 1024) return;
    int n = idx >> 10;
    int k = idx & 1023;
    float v = (n < VOCAB) ? w2[(size_t)k * VOCAB + n] : 0.f;
    Wt2p[idx] = (__bf16)v;
}

// ---------------- LSTM step (per-launch champion + 3 fixes) ----------------
// 128 batch x 256 gate-cols per block, 4 waves, 48KiB LDS, 2 blocks/CU.
// Grid (x=yb 16, y=rb 32): XCD = (yb + 16*rb)%8 = yb%8 -> per-XCD weight slice
// 1.1MB, L2-resident across steps (round-0 had rb on x -> 8.9MB thrash).
// c-state: private per-thread fragment layout, floatx4 access (coalesced).
// h epilogue: swizzled LDS transpose -> full-line dwordx4 stores (coalesced).
__global__ void __launch_bounds__(256, 2) lstm_step_kernel(
    const __bf16* __restrict__ xbf,
    const __bf16* __restrict__ Wtp,
    const float*  __restrict__ bias,
    const __bf16* __restrict__ hin,
    __bf16*       __restrict__ hout,
    float*        __restrict__ cstate,
    int t)
{
    __shared__ __bf16 As[128 * 64];      // 16 KiB (reused as h_lds in epilogue)
    __shared__ __bf16 Bs[2][128 * 64];   // 32 KiB

    const int tid  = threadIdx.x;
    const int wid  = tid >> 6;
    const int lane = tid & 63;
    const int ln   = lane & 15;
    const int lk   = lane >> 4;
    const int wm   = wid >> 1;
    const int wn   = wid & 1;
    const int yb   = blockIdx.x;   // unit-block pair {2yb, 2yb+1} -> XCD = yb%8
    const int rb   = blockIdx.y;   // batch block (128 rows)

    floatx4 acc[2][4][4];
#pragma unroll
    for (int p = 0; p < 2; ++p)
#pragma unroll
        for (int m = 0; m < 4; ++m)
#pragma unroll
            for (int g = 0; g < 4; ++g)
                acc[p][m][g] = (floatx4){0.f, 0.f, 0.f, 0.f};

    // XOR-swizzled staging: LDS chunk slot (row, kgs) holds global chunk (row, kgs ^ (row&7))
    int s_row[4], s_kgd[4];
#pragma unroll
    for (int q = 0; q < 4; ++q) {
        int flat = q * 256 + tid;
        int row  = flat >> 3;
        s_row[q] = row;
        s_kgd[q] = (flat & 7) ^ (row & 7);
    }

    for (int kt = 0; kt < 17; ++kt) {
        __syncthreads();
        // stage A (128 batch-rows x 64 k)
#pragma unroll
        for (int q = 0; q < 4; ++q) {
            const int row = s_row[q], kgd = s_kgd[q];
            const __bf16* gp;
            if (kt == 0)
                gp = xbf + (size_t)(rb * 128 + row) * (SEQ * FEAT) + t * FEAT + kgd * 8;
            else
                gp = hin + ((size_t)(rb * 128 + row) << 10) + (kt - 1) * 64 + kgd * 8;
            GLDS(gp, As + (size_t)(q * 256 + (wid << 6)) * 8);
        }
        // stage B tiles p=0,1 (Wtp rows yb*256 + p*128 + n)
#pragma unroll
        for (int p = 0; p < 2; ++p) {
#pragma unroll
            for (int q = 0; q < 4; ++q) {
                const int n = s_row[q], kgd = s_kgd[q];
                const __bf16* gp = Wtp + (size_t)(yb * 256 + p * 128 + n) * KLSTM + kt * 64 + kgd * 8;
                GLDS(gp, Bs[p] + (size_t)(q * 256 + (wid << 6)) * 8);
            }
        }
        __syncthreads();
        // compute
#pragma unroll
        for (int kk = 0; kk < 2; ++kk) {
            const int kg = kk * 4 + lk;
            bf16x8 a[4], b0[4], b1[4];
#pragma unroll
            for (int m = 0; m < 4; ++m) {
                int row  = wm * 64 + m * 16 + ln;
                int ccol = (kg ^ (row & 7)) * 8;
                a[m] = *(const bf16x8*)(As + row * 64 + ccol);
            }
#pragma unroll
            for (int g = 0; g < 4; ++g) {
                int n    = g * 32 + wn * 16 + ln;
                int ccol = (kg ^ (n & 7)) * 8;
                b0[g] = *(const bf16x8*)(Bs[0] + n * 64 + ccol);
                b1[g] = *(const bf16x8*)(Bs[1] + n * 64 + ccol);
            }
#pragma unroll
            for (int m = 0; m < 4; ++m)
#pragma unroll
                for (int g = 0; g < 4; ++g) {
                    acc[0][m][g] = MFMA(a[m], b0[g], acc[0][m][g], 0, 0, 0);
                    acc[1][m][g] = MFMA(a[m], b1[g], acc[1][m][g], 0, 0, 0);
                }
        }
    }

    // ---- fused LSTM epilogue ----
    // c: private fragment layout [block][thread][p*4+m] as floatx4 (coalesced vector RMW)
    // h: gates -> XOR-swizzled LDS transpose -> full-line dwordx4 stores
    __syncthreads();                     // all waves done reading As (last tile)
    {
        floatx4* cp = (floatx4*)cstate + ((size_t)(rb * 16 + yb) * 256 + tid) * 8;
        __bf16* h_lds = As;              // 128 x 64 bf16, cols XOR lk<<4
#pragma unroll
        for (int p = 0; p < 2; ++p) {
            const int u  = (yb * 2 + p) * 32 + wn * 16 + ln;
            const float bi  = bias[u];
            const float bfv = bias[UNITS + u];
            const float bg  = bias[2 * UNITS + u];
            const float bo  = bias[3 * UNITS + u];
            const int cl = (p * 32 + wn * 16 + ln) ^ (lk << 4);   // bank-conflict-free
#pragma unroll
            for (int m = 0; m < 4; ++m) {
                const int r0 = wm * 64 + m * 16 + lk * 4;
                floatx4 cold = cp[p * 4 + m];
                floatx4 cnew;
#pragma unroll
                for (int r = 0; r < 4; ++r) {
                    float ig = sigmoid_f(acc[p][m][0][r] + bi);
                    float fg = sigmoid_f(acc[p][m][1][r] + bfv);
                    float gg = tanh_f(acc[p][m][2][r] + bg);
                    float og = sigmoid_f(acc[p][m][3][r] + bo);
                    float cn = fg * cold[r] + ig * gg;
                    cnew[r] = cn;
                    h_lds[(r0 + r) * 64 + cl] = (__bf16)(og * tanh_f(cn));
                }
                cp[p * 4 + m] = cnew;
            }
        }
        __syncthreads();
#pragma unroll
        for (int j = 0; j < 4; ++j) {
            const int chunk = j * 256 + tid;          // 1024 16B-chunks
            const int lrow  = chunk >> 3;
            const int cof   = (chunk & 7) * 8;
            const int pcol  = cof ^ (((lrow >> 2) & 3) << 4);   // writer's lk == (row>>2)&3
            floatx4 v = *(const floatx4*)(h_lds + lrow * 64 + pcol);
            *(floatx4*)(hout + (size_t)(rb * 128 + lrow) * UNITS + yb * 64 + cof) = v;
        }
    }
}

// ---------------- final dense: [4096,1024] @ [1024,640] -> logits fp32 ----------------
__global__ void __launch_bounds__(256) dense_kernel(
    const __bf16* __restrict__ hin,
    const __bf16* __restrict__ Wt2p,
    float*        __restrict__ logits)
{
    __shared__ __bf16 As[128 * 64];
    __shared__ __bf16 Bs[128 * 64];

    const int tid  = threadIdx.x;
    const int wid  = tid >> 6;
    const int lane = tid & 63;
    const int ln   = lane & 15;
    const int lk   = lane >> 4;
    const int wm   = wid >> 1;
    const int wn   = wid & 1;
    const int rb   = blockIdx.x;
    const int nb   = blockIdx.y;

    floatx4 acc[4][4];
#pragma unroll
    for (int m = 0; m < 4; ++m)
#pragma unroll
        for (int g = 0; g < 4; ++g)
            acc[m][g] = (floatx4){0.f, 0.f, 0.f, 0.f};

    int s_row[4], s_kgd[4];
#pragma unroll
    for (int q = 0; q < 4; ++q) {
        int flat = q * 256 + tid;
        int row  = flat >> 3;
        s_row[q] = row;
        s_kgd[q] = (flat & 7) ^ (row & 7);
    }

    for (int kt = 0; kt < 16; ++kt) {
        __syncthreads();
#pragma unroll
        for (int q = 0; q < 4; ++q) {
            const int row = s_row[q], kgd = s_kgd[q];
            const __bf16* gp = hin + ((size_t)(rb * 128 + row) << 10) + kt * 64 + kgd * 8;
            GLDS(gp, As + (size_t)(q * 256 + (wid << 6)) * 8);
        }
#pragma unroll
        for (int q = 0; q < 4; ++q) {
            const int n = s_row[q], kgd = s_kgd[q];
            const __bf16* gp = Wt2p + ((size_t)(nb * 128 + n) << 10) + kt * 64 + kgd * 8;
            GLDS(gp, Bs + (size_t)(q * 256 + (wid << 6)) * 8);
        }
        __syncthreads();
#pragma unroll
        for (int kk = 0; kk < 2; ++kk) {
            const int kg = kk * 4 + lk;
            bf16x8 a[4], b[4];
#pragma unroll
            for (int m = 0; m < 4; ++m) {
                int row  = wm * 64 + m * 16 + ln;
                int ccol = (kg ^ (row & 7)) * 8;
                a[m] = *(const bf16x8*)(As + row * 64 + ccol);
            }
#pragma unroll
            for (int g = 0; g < 4; ++g) {
                int n    = g * 32 + wn * 16 + ln;
                int ccol = (kg ^ (n & 7)) * 8;
                b[g] = *(const bf16x8*)(Bs + n * 64 + ccol);
            }
#pragma unroll
            for (int m = 0; m < 4; ++m)
#pragma unroll
                for (int g = 0; g < 4; ++g)
                    acc[m][g] = MFMA(a[m], b[g], acc[m][g], 0, 0, 0);
        }
    }

#pragma unroll
    for (int m = 0; m < 4; ++m) {
        const int row0 = rb * 128 + wm * 64 + m * 16 + lk * 4;
#pragma unroll
        for (int g = 0; g < 4; ++g) {
            const int n = nb * 128 + g * 32 + wn * 16 + ln;
#pragma unroll
            for (int r = 0; r < 4; ++r)
                logits[(size_t)(row0 + r) * NPAD + n] = acc[m][g][r];
        }
    }
}

// ---------------- row softmax over 578 cols (+b2) ----------------
__global__ void __launch_bounds__(256) softmax_kernel(
    const float* __restrict__ logits,
    const float* __restrict__ b2,
    float* __restrict__ out)
{
    const int row = blockIdx.x;
    const int tid = threadIdx.x;
    __shared__ float red[8];

    float z[3];
    float lmax = -1e30f;
#pragma unroll
    for (int j = 0; j < 3; ++j) {
        int col = tid + j * 256;
        if (col < VOCAB) {
            z[j] = logits[(size_t)row * NPAD + col] + b2[col];
            lmax = fmaxf(lmax, z[j]);
        } else z[j] = -1e30f;
    }
    for (int off = 32; off > 0; off >>= 1) lmax = fmaxf(lmax, __shfl_xor(lmax, off));
    if ((tid & 63) == 0) red[tid >> 6] = lmax;
    __syncthreads();
    lmax = fmaxf(fmaxf(red[0], red[1]), fmaxf(red[2], red[3]));
    __syncthreads();

    float lsum = 0.f;
#pragma unroll
    for (int j = 0; j < 3; ++j) {
        int col = tid + j * 256;
        if (col < VOCAB) { z[j] = __expf(z[j] - lmax); lsum += z[j]; }
    }
    for (int off = 32; off > 0; off >>= 1) lsum += __shfl_xor(lsum, off);
    if ((tid & 63) == 0) red[tid >> 6] = lsum;
    __syncthreads();
    lsum = red[0] + red[1] + red[2] + red[3];
    float inv = 1.f / lsum;
#pragma unroll
    for (int j = 0; j < 3; ++j) {
        int col = tid + j * 256;
        if (col < VOCAB) out[(size_t)row * VOCAB + col] = z[j] * inv;
    }
}

// ---------------- launch ----------------
extern "C" void kernel_launch(void* const* d_in, const int* in_sizes, int n_in,
                              void* d_out, int out_size, void* d_ws, size_t ws_size,
                              hipStream_t stream)
{
    const float* x    = (const float*)d_in[0];
    const float* kern = (const float*)d_in[1];
    const float* reck = (const float*)d_in[2];
    const float* bias = (const float*)d_in[3];
    const float* w2   = (const float*)d_in[4];
    const float* b2   = (const float*)d_in[5];
    float* out = (float*)d_out;

    char* ws = (char*)d_ws;
    size_t off = 0;
    auto alloc = [&](size_t bytes) {
        char* p = ws + off;
        off += (bytes + 255) & ~(size_t)255;
        return p;
    };
    __bf16* Wtp    = (__bf16*)alloc((size_t)4096 * KLSTM * 2);
    __bf16* Wt2p   = (__bf16*)alloc((size_t)NPAD * 1024 * 2);
    __bf16* xbf    = (__bf16*)alloc((size_t)BATCH * SEQ * FEAT * 2);
    __bf16* h0     = (__bf16*)alloc((size_t)BATCH * UNITS * 2);
    __bf16* h1     = (__bf16*)alloc((size_t)BATCH * UNITS * 2);
    float*  cst    = (float*)alloc((size_t)BATCH * UNITS * 4);
    float*  logits = (float*)alloc((size_t)BATCH * NPAD * 4);
    if (off > ws_size) return;  // loud failure: output stays zero

    (void)hipMemsetAsync(h0, 0, (size_t)BATCH * UNITS * 2, stream);
    (void)hipMemsetAsync(cst, 0, (size_t)BATCH * UNITS * 4, stream);

    convert_x_kernel<<<(BATCH * SEQ * FEAT / 4 + 255) / 256, 256, 0, stream>>>(x, xbf);
    convert_weights_kernel<<<(4096 * KLSTM + 255) / 256, 256, 0, stream>>>(kern, reck, Wtp);
    convert_w2_kernel<<<(NPAD * 1024 + 255) / 256, 256, 0, stream>>>(w2, Wt2p);

    __bf16* hin = h0; __bf16* hout = h1;
    for (int t = 0; t < SEQ; ++t) {
        lstm_step_kernel<<<dim3(16, 32), 256, 0, stream>>>(xbf, Wtp, bias, hin, hout, cst, t);
        __bf16* tmp = hin; hin = hout; hout = tmp;
    }

    dense_kernel<<<dim3(32, 5), 256, 0, stream>>>(hin, Wt2p, logits);
    softmax_kernel<<<BATCH, 256, 0, stream>>>(logits, b2, out);
}